// Round 1
// baseline (1470.633 us; speedup 1.0000x reference)
//
#include <hip/hip_runtime.h>
#include <hip/hip_bf16.h>

#define NN 100000
#define EE 1600000
#define ETOT (NN + EE)
#define HID 128
#define HEADS 8
#define CH 16
#define EPS_BN 1e-5f
#define NEG_SLOPE 0.2f

// ---------------- CSR build ----------------

__global__ void init_counts(int* counts) {
    int i = blockIdx.x * blockDim.x + threadIdx.x;
    if (i < NN) counts[i] = 1;  // self-loop
}

__global__ void hist_kernel(const int* __restrict__ ei, int* counts) {
    int i = blockIdx.x * blockDim.x + threadIdx.x;
    if (i < EE) atomicAdd(&counts[ei[EE + i]], 1);
}

__global__ void scan1(const int* __restrict__ counts, int* incl, int* bsum) {
    __shared__ int s[256];
    int g = blockIdx.x * 256 + threadIdx.x;
    s[threadIdx.x] = (g < NN) ? counts[g] : 0;
    __syncthreads();
    for (int off = 1; off < 256; off <<= 1) {
        int add = (threadIdx.x >= off) ? s[threadIdx.x - off] : 0;
        __syncthreads();
        s[threadIdx.x] += add;
        __syncthreads();
    }
    if (g < NN) incl[g] = s[threadIdx.x];
    if (threadIdx.x == 255) bsum[blockIdx.x] = s[255];
}

__global__ void scan2(int* bsum, int nb) {
    __shared__ int s[512];
    s[threadIdx.x] = (threadIdx.x < nb) ? bsum[threadIdx.x] : 0;
    __syncthreads();
    for (int off = 1; off < 512; off <<= 1) {
        int add = (threadIdx.x >= off) ? s[threadIdx.x - off] : 0;
        __syncthreads();
        s[threadIdx.x] += add;
        __syncthreads();
    }
    if (threadIdx.x < nb) bsum[threadIdx.x] = s[threadIdx.x];
}

__global__ void scan3(const int* __restrict__ incl, const int* __restrict__ bsum,
                      const int* __restrict__ counts, int* rowptr, int* cursor) {
    int g = blockIdx.x * blockDim.x + threadIdx.x;
    if (g < NN) {
        int b = g >> 8;
        int val = incl[g] + (b > 0 ? bsum[b - 1] : 0);
        rowptr[g + 1] = val;
        cursor[g] = val - counts[g];
        if (g == 0) rowptr[0] = 0;
    }
}

__global__ void fill_kernel(const int* __restrict__ ei, int* cursor, int* csrc) {
    int i = blockIdx.x * blockDim.x + threadIdx.x;
    if (i >= ETOT) return;
    int s, d;
    if (i < EE) { s = ei[i]; d = ei[EE + i]; }
    else        { s = i - EE; d = s; }
    int pos = atomicAdd(&cursor[d], 1);
    csrc[pos] = s;
}

// ---------------- GEMM: C(M,128) = A(M,K) @ B(K,128) [+bias][+elu] ----------------

#define BM 128
#define BK 16

__global__ __launch_bounds__(256) void gemm_kernel(
    const float* __restrict__ A, const float* __restrict__ B,
    float* __restrict__ C, int M, int K,
    const float* __restrict__ bias, int do_elu)
{
    __shared__ float As[BK][BM];   // k-major (transposed)
    __shared__ float Bs[BK][128];
    int t = threadIdx.x;
    int row0 = blockIdx.x * BM;
    int tx = t & 15, ty = t >> 4;
    float acc[8][8] = {};

    for (int k0 = 0; k0 < K; k0 += BK) {
        // stage A: 128 rows x 16 k  (512 float4s, 2 per thread)
        #pragma unroll
        for (int j = 0; j < 2; ++j) {
            int i4 = t * 2 + j;
            int row = i4 >> 2, kc = (i4 & 3) * 4;
            float4 v = make_float4(0.f, 0.f, 0.f, 0.f);
            int gr = row0 + row;
            if (gr < M) v = *(const float4*)(A + (size_t)gr * K + k0 + kc);
            As[kc + 0][row] = v.x;
            As[kc + 1][row] = v.y;
            As[kc + 2][row] = v.z;
            As[kc + 3][row] = v.w;
        }
        // stage B: 16 rows x 128 cols
        #pragma unroll
        for (int j = 0; j < 2; ++j) {
            int i4 = t * 2 + j;
            int kr = i4 >> 5, col = (i4 & 31) * 4;
            float4 v = *(const float4*)(B + (size_t)(k0 + kr) * 128 + col);
            *(float4*)&Bs[kr][col] = v;
        }
        __syncthreads();
        #pragma unroll
        for (int k = 0; k < BK; ++k) {
            float a[8], b[8];
            *(float4*)&a[0] = *(const float4*)&As[k][ty * 8];
            *(float4*)&a[4] = *(const float4*)&As[k][ty * 8 + 4];
            *(float4*)&b[0] = *(const float4*)&Bs[k][tx * 8];
            *(float4*)&b[4] = *(const float4*)&Bs[k][tx * 8 + 4];
            #pragma unroll
            for (int i = 0; i < 8; ++i)
                #pragma unroll
                for (int j = 0; j < 8; ++j)
                    acc[i][j] += a[i] * b[j];
        }
        __syncthreads();
    }

    #pragma unroll
    for (int i = 0; i < 8; ++i) {
        int gr = row0 + ty * 8 + i;
        if (gr >= M) continue;
        #pragma unroll
        for (int j = 0; j < 8; j += 4) {
            int col = tx * 8 + j;
            float4 v = make_float4(acc[i][j], acc[i][j+1], acc[i][j+2], acc[i][j+3]);
            if (bias) {
                v.x += bias[col]; v.y += bias[col+1]; v.z += bias[col+2]; v.w += bias[col+3];
            }
            if (do_elu) {
                v.x = v.x > 0.f ? v.x : __expf(v.x) - 1.f;
                v.y = v.y > 0.f ? v.y : __expf(v.y) - 1.f;
                v.z = v.z > 0.f ? v.z : __expf(v.z) - 1.f;
                v.w = v.w > 0.f ? v.w : __expf(v.w) - 1.f;
            }
            *(float4*)(C + (size_t)gr * 128 + col) = v;
        }
    }
}

// ---------------- attention logits ----------------

__global__ void compute_al(const float* __restrict__ h2, const float* __restrict__ a_s,
                           const float* __restrict__ a_d, float* __restrict__ al_s,
                           float* __restrict__ al_d) {
    int i = blockIdx.x * blockDim.x + threadIdx.x;
    if (i >= NN * HEADS) return;
    int hh = i & 7, nd = i >> 3;
    const float* hp = h2 + (size_t)nd * HID + hh * CH;
    const float* sp = a_s + hh * CH;
    const float* dp = a_d + hh * CH;
    float s1 = 0.f, s2 = 0.f;
    #pragma unroll
    for (int c = 0; c < CH; ++c) {
        float hv = hp[c];
        s1 += hv * sp[c];
        s2 += hv * dp[c];
    }
    al_s[i] = s1;
    al_d[i] = s2;
}

// ---------------- GAT aggregation: one wave per destination node ----------------
// softmax without max-subtraction: |e| is small (att weights ~0.05), exp safe in fp32.

__global__ __launch_bounds__(256) void gat_agg(
    const int* __restrict__ rowptr, const int* __restrict__ csrc,
    const float* __restrict__ h2, const float* __restrict__ al_s,
    const float* __restrict__ al_d, const float* __restrict__ bias,
    float* __restrict__ out)
{
    int wv = (blockIdx.x * blockDim.x + threadIdx.x) >> 6;
    int lane = threadIdx.x & 63;
    if (wv >= NN) return;
    int v = wv;
    int e0 = rowptr[v], e1 = rowptr[v + 1];
    int head = lane >> 3;        // channels 2*lane, 2*lane+1 are both in this head
    int ch = lane * 2;
    float ald = al_d[v * HEADS + head];
    float acc0 = 0.f, acc1 = 0.f, denom = 0.f;
    for (int e = e0; e < e1; ++e) {
        int s = csrc[e];
        float als = al_s[s * HEADS + head];
        float x = als + ald;
        float lr = x > 0.f ? x : NEG_SLOPE * x;
        float w = __expf(lr);
        float2 hv = *(const float2*)(h2 + (size_t)s * HID + ch);
        acc0 += w * hv.x;
        acc1 += w * hv.y;
        denom += w;              // all 8 lanes of a head group compute identical w
    }
    float inv = 1.0f / (denom + 1e-16f);
    out[(size_t)v * HID + ch]     = acc0 * inv + bias[ch];
    out[(size_t)v * HID + ch + 1] = acc1 * inv + bias[ch + 1];
}

// ---------------- batchnorm ----------------

__global__ void bn_stats(const float* __restrict__ a, float* stats) {
    int t = threadIdx.x;  // 128 threads
    float s = 0.f, q = 0.f;
    for (int r = blockIdx.x; r < NN; r += gridDim.x) {
        float v = a[(size_t)r * HID + t];
        s += v;
        q += v * v;
    }
    atomicAdd(&stats[t], s);
    atomicAdd(&stats[HID + t], q);
}

__global__ void bn_apply(const float* __restrict__ a, const float* __restrict__ stats,
                         const float* __restrict__ g, const float* __restrict__ be,
                         float* __restrict__ h) {
    int i = blockIdx.x * blockDim.x + threadIdx.x;  // NN*32 threads, 4 channels each
    if (i >= NN * 32) return;
    int c4 = (i & 31) * 4;
    int nd = i >> 5;
    float4 v = *(const float4*)(a + (size_t)nd * HID + c4);
    float4 r = *(const float4*)(h + (size_t)nd * HID + c4);
    float vv[4] = {v.x, v.y, v.z, v.w};
    float rr[4] = {r.x, r.y, r.z, r.w};
    float o[4];
    #pragma unroll
    for (int j = 0; j < 4; ++j) {
        int c = c4 + j;
        float mu = stats[c] * (1.0f / NN);
        float var = stats[HID + c] * (1.0f / NN) - mu * mu;
        float rs = rsqrtf(var + EPS_BN);
        float x = (vv[j] - mu) * rs * g[c] + be[c];
        x = x > 0.f ? x : __expf(x) - 1.f;
        o[j] = x + rr[j];
    }
    *(float4*)(h + (size_t)nd * HID + c4) = make_float4(o[0], o[1], o[2], o[3]);
}

// ---------------- final FC: out[n] = h[n,:] . w + b  (one wave per node) ----------------

__global__ __launch_bounds__(256) void fc_kernel(
    const float* __restrict__ h, const float* __restrict__ w,
    const float* __restrict__ b, float* __restrict__ out)
{
    int wv = (blockIdx.x * blockDim.x + threadIdx.x) >> 6;
    int lane = threadIdx.x & 63;
    if (wv >= NN) return;
    float2 hv = *(const float2*)(h + (size_t)wv * HID + lane * 2);
    float2 wl = *(const float2*)(w + lane * 2);
    float acc = hv.x * wl.x + hv.y * wl.y;
    #pragma unroll
    for (int off = 32; off > 0; off >>= 1)
        acc += __shfl_down(acc, off, 64);
    if (lane == 0) out[wv] = acc + b[0];
}

// ---------------- launch ----------------

extern "C" void kernel_launch(void* const* d_in, const int* in_sizes, int n_in,
                              void* d_out, int out_size, void* d_ws, size_t ws_size,
                              hipStream_t stream) {
    const float* x       = (const float*)d_in[0];
    const int*   ei      = (const int*)  d_in[1];
    const float* proj_w  = (const float*)d_in[2];
    const float* proj_b  = (const float*)d_in[3];
    const float* W       = (const float*)d_in[4];
    const float* att_src = (const float*)d_in[5];
    const float* att_dst = (const float*)d_in[6];
    const float* conv_b  = (const float*)d_in[7];
    const float* bn_g    = (const float*)d_in[8];
    const float* bn_b    = (const float*)d_in[9];
    const float* fc_w    = (const float*)d_in[10];
    const float* fc_b    = (const float*)d_in[11];
    float* out = (float*)d_out;

    char* p = (char*)d_ws;
    float* h    = (float*)p; p += (size_t)NN * HID * 4;
    float* h2   = (float*)p; p += (size_t)NN * HID * 4;
    float* agg  = (float*)p; p += (size_t)NN * HID * 4;
    float* al_s = (float*)p; p += (size_t)NN * HEADS * 4;
    float* al_d = (float*)p; p += (size_t)NN * HEADS * 4;
    int* counts = (int*)p;   p += (size_t)NN * 4;
    int* incl   = (int*)p;   p += (size_t)NN * 4;
    int* bsum   = (int*)p;   p += 1024 * 4;
    int* rowptr = (int*)p;   p += (size_t)(NN + 1) * 4 + 252;  // keep alignment
    int* cursor = (int*)p;   p += (size_t)NN * 4;
    int* csrc   = (int*)p;   p += (size_t)ETOT * 4;
    float* stats = (float*)p; p += 256 * 4;
    (void)ws_size; (void)n_in; (void)in_sizes; (void)out_size;

    const int nbN = (NN + 255) / 256;          // 391
    // --- CSR build (graph shared by all 3 layers) ---
    init_counts<<<nbN, 256, 0, stream>>>(counts);
    hist_kernel<<<(EE + 255) / 256, 256, 0, stream>>>(ei, counts);
    scan1<<<nbN, 256, 0, stream>>>(counts, incl, bsum);
    scan2<<<1, 512, 0, stream>>>(bsum, nbN);
    scan3<<<nbN, 256, 0, stream>>>(incl, bsum, counts, rowptr, cursor);
    fill_kernel<<<(ETOT + 255) / 256, 256, 0, stream>>>(ei, cursor, csrc);

    // --- initial projection: h = elu(x @ proj_w + proj_b) ---
    gemm_kernel<<<(NN + BM - 1) / BM, 256, 0, stream>>>(x, proj_w, h, NN, 256, proj_b, 1);

    for (int l = 0; l < 3; ++l) {
        const float* Wl  = W + (size_t)l * HID * HID;
        const float* asl = att_src + (size_t)l * HEADS * CH;
        const float* adl = att_dst + (size_t)l * HEADS * CH;
        const float* cbl = conv_b + (size_t)l * HID;
        const float* gl  = bn_g + (size_t)l * HID;
        const float* bl  = bn_b + (size_t)l * HID;

        gemm_kernel<<<(NN + BM - 1) / BM, 256, 0, stream>>>(h, Wl, h2, NN, 128, nullptr, 0);
        compute_al<<<(NN * HEADS + 255) / 256, 256, 0, stream>>>(h2, asl, adl, al_s, al_d);
        gat_agg<<<(NN + 3) / 4, 256, 0, stream>>>(rowptr, csrc, h2, al_s, al_d, cbl, agg);
        hipMemsetAsync(stats, 0, 256 * 4, stream);
        bn_stats<<<512, 128, 0, stream>>>(agg, stats);
        bn_apply<<<(NN * 32 + 255) / 256, 256, 0, stream>>>(agg, stats, gl, bl, h);
    }

    fc_kernel<<<(NN + 3) / 4, 256, 0, stream>>>(h, fc_w, fc_b, out);
}

// Round 2
// 1160.798 us; speedup vs baseline: 1.2669x; 1.2669x over previous
//
#include <hip/hip_runtime.h>
#include <hip/hip_bf16.h>

#define NN 100000
#define EE 1600000
#define ETOT (NN + EE)
#define HID 128
#define HEADS 8
#define CH 16
#define EPS_BN 1e-5f
#define NEG_SLOPE 0.2f

__device__ inline unsigned int f2bf(float x) {
    __hip_bfloat16 b = __float2bfloat16(x);
    return (unsigned int)*reinterpret_cast<unsigned short*>(&b);
}

// ---------------- CSR build ----------------

__global__ void init_counts(int* counts) {
    int i = blockIdx.x * blockDim.x + threadIdx.x;
    if (i < NN) counts[i] = 1;  // self-loop
}

__global__ void hist_kernel(const int* __restrict__ ei, int* counts) {
    int i = blockIdx.x * blockDim.x + threadIdx.x;
    if (i < EE) atomicAdd(&counts[ei[EE + i]], 1);
}

__global__ void scan1(const int* __restrict__ counts, int* incl, int* bsum) {
    __shared__ int s[256];
    int g = blockIdx.x * 256 + threadIdx.x;
    s[threadIdx.x] = (g < NN) ? counts[g] : 0;
    __syncthreads();
    for (int off = 1; off < 256; off <<= 1) {
        int add = (threadIdx.x >= off) ? s[threadIdx.x - off] : 0;
        __syncthreads();
        s[threadIdx.x] += add;
        __syncthreads();
    }
    if (g < NN) incl[g] = s[threadIdx.x];
    if (threadIdx.x == 255) bsum[blockIdx.x] = s[255];
}

__global__ void scan2(int* bsum, int nb) {
    __shared__ int s[512];
    s[threadIdx.x] = (threadIdx.x < nb) ? bsum[threadIdx.x] : 0;
    __syncthreads();
    for (int off = 1; off < 512; off <<= 1) {
        int add = (threadIdx.x >= off) ? s[threadIdx.x - off] : 0;
        __syncthreads();
        s[threadIdx.x] += add;
        __syncthreads();
    }
    if (threadIdx.x < nb) bsum[threadIdx.x] = s[threadIdx.x];
}

__global__ void scan3(const int* __restrict__ incl, const int* __restrict__ bsum,
                      const int* __restrict__ counts, int* rowptr, int* cursor) {
    int g = blockIdx.x * blockDim.x + threadIdx.x;
    if (g < NN) {
        int b = g >> 8;
        int val = incl[g] + (b > 0 ? bsum[b - 1] : 0);
        rowptr[g + 1] = val;
        cursor[g] = val - counts[g];
        if (g == 0) rowptr[0] = 0;
    }
}

__global__ void fill_kernel(const int* __restrict__ ei, int* cursor, int* csrc) {
    int i = blockIdx.x * blockDim.x + threadIdx.x;
    if (i >= ETOT) return;
    int s, d;
    if (i < EE) { s = ei[i]; d = ei[EE + i]; }
    else        { s = i - EE; d = s; }
    int pos = atomicAdd(&cursor[d], 1);
    csrc[pos] = s;
}

// ---------------- GEMM: C(M,128) = A(M,K) @ B(K,128) [+bias][+elu][+bf16 copy] ----

#define BM 128
#define BK 16

__global__ __launch_bounds__(256) void gemm_kernel(
    const float* __restrict__ A, const float* __restrict__ B,
    float* __restrict__ C, int M, int K,
    const float* __restrict__ bias, int do_elu,
    unsigned int* __restrict__ Cb)   // optional bf16x2-packed copy [M,64] uints
{
    __shared__ float As[BK][BM];   // k-major (transposed)
    __shared__ float Bs[BK][128];
    int t = threadIdx.x;
    int row0 = blockIdx.x * BM;
    int tx = t & 15, ty = t >> 4;
    float acc[8][8] = {};

    for (int k0 = 0; k0 < K; k0 += BK) {
        #pragma unroll
        for (int j = 0; j < 2; ++j) {
            int i4 = t * 2 + j;
            int row = i4 >> 2, kc = (i4 & 3) * 4;
            float4 v = make_float4(0.f, 0.f, 0.f, 0.f);
            int gr = row0 + row;
            if (gr < M) v = *(const float4*)(A + (size_t)gr * K + k0 + kc);
            As[kc + 0][row] = v.x;
            As[kc + 1][row] = v.y;
            As[kc + 2][row] = v.z;
            As[kc + 3][row] = v.w;
        }
        #pragma unroll
        for (int j = 0; j < 2; ++j) {
            int i4 = t * 2 + j;
            int kr = i4 >> 5, col = (i4 & 31) * 4;
            float4 v = *(const float4*)(B + (size_t)(k0 + kr) * 128 + col);
            *(float4*)&Bs[kr][col] = v;
        }
        __syncthreads();
        #pragma unroll
        for (int k = 0; k < BK; ++k) {
            float a[8], b[8];
            *(float4*)&a[0] = *(const float4*)&As[k][ty * 8];
            *(float4*)&a[4] = *(const float4*)&As[k][ty * 8 + 4];
            *(float4*)&b[0] = *(const float4*)&Bs[k][tx * 8];
            *(float4*)&b[4] = *(const float4*)&Bs[k][tx * 8 + 4];
            #pragma unroll
            for (int i = 0; i < 8; ++i)
                #pragma unroll
                for (int j = 0; j < 8; ++j)
                    acc[i][j] += a[i] * b[j];
        }
        __syncthreads();
    }

    #pragma unroll
    for (int i = 0; i < 8; ++i) {
        int gr = row0 + ty * 8 + i;
        if (gr >= M) continue;
        #pragma unroll
        for (int j = 0; j < 8; j += 4) {
            int col = tx * 8 + j;
            float4 v = make_float4(acc[i][j], acc[i][j+1], acc[i][j+2], acc[i][j+3]);
            if (bias) {
                v.x += bias[col]; v.y += bias[col+1]; v.z += bias[col+2]; v.w += bias[col+3];
            }
            if (do_elu) {
                v.x = v.x > 0.f ? v.x : __expf(v.x) - 1.f;
                v.y = v.y > 0.f ? v.y : __expf(v.y) - 1.f;
                v.z = v.z > 0.f ? v.z : __expf(v.z) - 1.f;
                v.w = v.w > 0.f ? v.w : __expf(v.w) - 1.f;
            }
            *(float4*)(C + (size_t)gr * 128 + col) = v;
            if (Cb) {
                unsigned int u0 = (f2bf(v.y) << 16) | f2bf(v.x);
                unsigned int u1 = (f2bf(v.w) << 16) | f2bf(v.z);
                *(uint2*)(Cb + (size_t)gr * 64 + (col >> 1)) = make_uint2(u0, u1);
            }
        }
    }
}

// ---------------- attention logits (fp32 h2) ----------------

__global__ void compute_al(const float* __restrict__ h2, const float* __restrict__ a_s,
                           const float* __restrict__ a_d, float* __restrict__ al_s,
                           float* __restrict__ al_d) {
    int i = blockIdx.x * blockDim.x + threadIdx.x;
    if (i >= NN * HEADS) return;
    int hh = i & 7, nd = i >> 3;
    const float* hp = h2 + (size_t)nd * HID + hh * CH;
    const float* sp = a_s + hh * CH;
    const float* dp = a_d + hh * CH;
    float s1 = 0.f, s2 = 0.f;
    #pragma unroll
    for (int c = 0; c < CH; ++c) {
        float hv = hp[c];
        s1 += hv * sp[c];
        s2 += hv * dp[c];
    }
    al_s[i] = s1;
    al_d[i] = s2;
}

// ---------------- GAT aggregation: one wave per dst node, bf16 gather, 4x unroll ----

__global__ __launch_bounds__(256) void gat_agg(
    const int* __restrict__ rowptr, const int* __restrict__ csrc,
    const unsigned int* __restrict__ h2b, const float* __restrict__ al_s,
    const float* __restrict__ al_d, const float* __restrict__ bias,
    float* __restrict__ out)
{
    int wv = (blockIdx.x * blockDim.x + threadIdx.x) >> 6;
    int lane = threadIdx.x & 63;
    if (wv >= NN) return;
    int e0 = rowptr[wv], e1 = rowptr[wv + 1];
    int head = lane >> 3;
    int ch = lane * 2;
    float ald = al_d[wv * HEADS + head];
    float acc0 = 0.f, acc1 = 0.f, denom = 0.f;

    int e = e0;
    for (; e + 4 <= e1; e += 4) {
        int s0 = csrc[e], s1 = csrc[e + 1], s2 = csrc[e + 2], s3 = csrc[e + 3];
        float a0 = al_s[s0 * HEADS + head];
        float a1 = al_s[s1 * HEADS + head];
        float a2 = al_s[s2 * HEADS + head];
        float a3 = al_s[s3 * HEADS + head];
        unsigned int p0 = h2b[(size_t)s0 * 64 + lane];
        unsigned int p1 = h2b[(size_t)s1 * 64 + lane];
        unsigned int p2 = h2b[(size_t)s2 * 64 + lane];
        unsigned int p3 = h2b[(size_t)s3 * 64 + lane];
        float x0 = a0 + ald; x0 = x0 > 0.f ? x0 : NEG_SLOPE * x0; float w0 = __expf(x0);
        float x1 = a1 + ald; x1 = x1 > 0.f ? x1 : NEG_SLOPE * x1; float w1 = __expf(x1);
        float x2 = a2 + ald; x2 = x2 > 0.f ? x2 : NEG_SLOPE * x2; float w2 = __expf(x2);
        float x3 = a3 + ald; x3 = x3 > 0.f ? x3 : NEG_SLOPE * x3; float w3 = __expf(x3);
        acc0 += w0 * __uint_as_float(p0 << 16);
        acc1 += w0 * __uint_as_float(p0 & 0xffff0000u);
        acc0 += w1 * __uint_as_float(p1 << 16);
        acc1 += w1 * __uint_as_float(p1 & 0xffff0000u);
        acc0 += w2 * __uint_as_float(p2 << 16);
        acc1 += w2 * __uint_as_float(p2 & 0xffff0000u);
        acc0 += w3 * __uint_as_float(p3 << 16);
        acc1 += w3 * __uint_as_float(p3 & 0xffff0000u);
        denom += w0 + w1 + w2 + w3;
    }
    for (; e < e1; ++e) {
        int s = csrc[e];
        float a = al_s[s * HEADS + head];
        unsigned int p = h2b[(size_t)s * 64 + lane];
        float x = a + ald; x = x > 0.f ? x : NEG_SLOPE * x;
        float w = __expf(x);
        acc0 += w * __uint_as_float(p << 16);
        acc1 += w * __uint_as_float(p & 0xffff0000u);
        denom += w;
    }
    float inv = 1.0f / (denom + 1e-16f);
    out[(size_t)wv * HID + ch]     = acc0 * inv + bias[ch];
    out[(size_t)wv * HID + ch + 1] = acc1 * inv + bias[ch + 1];
}

// ---------------- batchnorm ----------------

__global__ void bn_stats(const float* __restrict__ a, float* stats) {
    int t = threadIdx.x;  // 128 threads
    float s = 0.f, q = 0.f;
    for (int r = blockIdx.x; r < NN; r += gridDim.x) {
        float v = a[(size_t)r * HID + t];
        s += v;
        q += v * v;
    }
    atomicAdd(&stats[t], s);
    atomicAdd(&stats[HID + t], q);
}

__global__ void bn_apply(const float* __restrict__ a, const float* __restrict__ stats,
                         const float* __restrict__ g, const float* __restrict__ be,
                         float* __restrict__ h) {
    int i = blockIdx.x * blockDim.x + threadIdx.x;
    if (i >= NN * 32) return;
    int c4 = (i & 31) * 4;
    int nd = i >> 5;
    float4 v = *(const float4*)(a + (size_t)nd * HID + c4);
    float4 r = *(const float4*)(h + (size_t)nd * HID + c4);
    float vv[4] = {v.x, v.y, v.z, v.w};
    float rr[4] = {r.x, r.y, r.z, r.w};
    float o[4];
    #pragma unroll
    for (int j = 0; j < 4; ++j) {
        int c = c4 + j;
        float mu = stats[c] * (1.0f / NN);
        float var = stats[HID + c] * (1.0f / NN) - mu * mu;
        float rs = rsqrtf(var + EPS_BN);
        float x = (vv[j] - mu) * rs * g[c] + be[c];
        x = x > 0.f ? x : __expf(x) - 1.f;
        o[j] = x + rr[j];
    }
    *(float4*)(h + (size_t)nd * HID + c4) = make_float4(o[0], o[1], o[2], o[3]);
}

// ---------------- final FC ----------------

__global__ __launch_bounds__(256) void fc_kernel(
    const float* __restrict__ h, const float* __restrict__ w,
    const float* __restrict__ b, float* __restrict__ out)
{
    int wv = (blockIdx.x * blockDim.x + threadIdx.x) >> 6;
    int lane = threadIdx.x & 63;
    if (wv >= NN) return;
    float2 hv = *(const float2*)(h + (size_t)wv * HID + lane * 2);
    float2 wl = *(const float2*)(w + lane * 2);
    float acc = hv.x * wl.x + hv.y * wl.y;
    #pragma unroll
    for (int off = 32; off > 0; off >>= 1)
        acc += __shfl_down(acc, off, 64);
    if (lane == 0) out[wv] = acc + b[0];
}

// ---------------- launch ----------------

extern "C" void kernel_launch(void* const* d_in, const int* in_sizes, int n_in,
                              void* d_out, int out_size, void* d_ws, size_t ws_size,
                              hipStream_t stream) {
    const float* x       = (const float*)d_in[0];
    const int*   ei      = (const int*)  d_in[1];
    const float* proj_w  = (const float*)d_in[2];
    const float* proj_b  = (const float*)d_in[3];
    const float* W       = (const float*)d_in[4];
    const float* att_src = (const float*)d_in[5];
    const float* att_dst = (const float*)d_in[6];
    const float* conv_b  = (const float*)d_in[7];
    const float* bn_g    = (const float*)d_in[8];
    const float* bn_b    = (const float*)d_in[9];
    const float* fc_w    = (const float*)d_in[10];
    const float* fc_b    = (const float*)d_in[11];
    float* out = (float*)d_out;

    char* p = (char*)d_ws;
    float* h    = (float*)p; p += (size_t)NN * HID * 4;
    float* h2   = (float*)p; p += (size_t)NN * HID * 4;   // fp32 GEMM out; reused as agg
    float* agg  = h2;                                      // alias: h2 dead after compute_al
    unsigned int* h2b = (unsigned int*)p; p += (size_t)NN * 64 * 4;  // bf16x2 packed
    float* al_s = (float*)p; p += (size_t)NN * HEADS * 4;
    float* al_d = (float*)p; p += (size_t)NN * HEADS * 4;
    int* counts = (int*)p;   p += (size_t)NN * 4;
    int* incl   = (int*)p;   p += (size_t)NN * 4;
    int* bsum   = (int*)p;   p += 1024 * 4;
    int* rowptr = (int*)p;   p += (size_t)(NN + 1) * 4 + 252;
    int* cursor = (int*)p;   p += (size_t)NN * 4;
    int* csrc   = (int*)p;   p += (size_t)ETOT * 4;
    float* stats = (float*)p; p += 256 * 4;
    (void)ws_size; (void)n_in; (void)in_sizes; (void)out_size;

    const int nbN = (NN + 255) / 256;
    init_counts<<<nbN, 256, 0, stream>>>(counts);
    hist_kernel<<<(EE + 255) / 256, 256, 0, stream>>>(ei, counts);
    scan1<<<nbN, 256, 0, stream>>>(counts, incl, bsum);
    scan2<<<1, 512, 0, stream>>>(bsum, nbN);
    scan3<<<nbN, 256, 0, stream>>>(incl, bsum, counts, rowptr, cursor);
    fill_kernel<<<(ETOT + 255) / 256, 256, 0, stream>>>(ei, cursor, csrc);

    gemm_kernel<<<(NN + BM - 1) / BM, 256, 0, stream>>>(x, proj_w, h, NN, 256, proj_b, 1, nullptr);

    for (int l = 0; l < 3; ++l) {
        const float* Wl  = W + (size_t)l * HID * HID;
        const float* asl = att_src + (size_t)l * HEADS * CH;
        const float* adl = att_dst + (size_t)l * HEADS * CH;
        const float* cbl = conv_b + (size_t)l * HID;
        const float* gl  = bn_g + (size_t)l * HID;
        const float* bl  = bn_b + (size_t)l * HID;

        gemm_kernel<<<(NN + BM - 1) / BM, 256, 0, stream>>>(h, Wl, h2, NN, 128, nullptr, 0, h2b);
        compute_al<<<(NN * HEADS + 255) / 256, 256, 0, stream>>>(h2, asl, adl, al_s, al_d);
        gat_agg<<<(NN + 3) / 4, 256, 0, stream>>>(rowptr, csrc, h2b, al_s, al_d, cbl, agg);
        hipMemsetAsync(stats, 0, 256 * 4, stream);
        bn_stats<<<512, 128, 0, stream>>>(agg, stats);
        bn_apply<<<(NN * 32 + 255) / 256, 256, 0, stream>>>(agg, stats, gl, bl, h);
    }

    fc_kernel<<<(NN + 3) / 4, 256, 0, stream>>>(h, fc_w, fc_b, out);
}

// Round 3
// 906.199 us; speedup vs baseline: 1.6229x; 1.2810x over previous
//
#include <hip/hip_runtime.h>
#include <hip/hip_bf16.h>

#define NN 100000
#define EE 1600000
#define ETOT (NN + EE)
#define HID 128
#define HEADS 8
#define CH 16
#define EPS_BN 1e-5f
#define NEG_SLOPE 0.2f
#define NB 196            // buckets of 512 dst nodes
#define NBLK_A 208        // ceil(ETOT / 8192)

typedef unsigned short ushort_t;
typedef unsigned int uint_t;
typedef __attribute__((ext_vector_type(8))) short short8;
typedef __attribute__((ext_vector_type(4))) float float4v;

__device__ inline uint_t f2bf(float x) {
    __hip_bfloat16 b = __float2bfloat16(x);
    return (uint_t)*reinterpret_cast<unsigned short*>(&b);
}
__device__ inline uint_t pack2(float lo, float hi) {
    return f2bf(lo) | (f2bf(hi) << 16);
}

// ================= CSR build: bucketed counting sort =================

__global__ __launch_bounds__(256) void bucket_hist(const int* __restrict__ ei, int* bcnt) {
    __shared__ int h[256];
    int t = threadIdx.x;
    h[t] = 0;
    __syncthreads();
    int base = blockIdx.x * 8192;
    #pragma unroll 4
    for (int j = 0; j < 32; ++j) {
        int i = base + j * 256 + t;
        if (i < ETOT) {
            int d = (i < EE) ? ei[EE + i] : (i - EE);
            atomicAdd(&h[d >> 9], 1);
        }
    }
    __syncthreads();
    if (t < NB && h[t]) atomicAdd(&bcnt[t], h[t]);
}

__global__ void bucket_scan(const int* __restrict__ bcnt, int* bbase, int* bcursor, int* rowptr) {
    __shared__ int s[256];
    int t = threadIdx.x;
    int orig = (t < NB) ? bcnt[t] : 0;
    s[t] = orig;
    __syncthreads();
    for (int off = 1; off < 256; off <<= 1) {
        int add = (t >= off) ? s[t - off] : 0;
        __syncthreads();
        s[t] += add;
        __syncthreads();
    }
    int excl = s[t] - orig;
    if (t < NB) { bbase[t] = excl; bcursor[t] = excl; }
    if (t == 0) { bbase[NB] = ETOT; rowptr[NN] = ETOT; }
}

__global__ __launch_bounds__(256) void bucket_scatter(const int* __restrict__ ei,
                                                      int* bcursor, uint2* __restrict__ pairs) {
    __shared__ int h[256];
    __shared__ int lbase[256];
    int t = threadIdx.x;
    h[t] = 0;
    __syncthreads();
    int base = blockIdx.x * 8192;
    #pragma unroll 4
    for (int j = 0; j < 32; ++j) {
        int i = base + j * 256 + t;
        if (i < ETOT) {
            int d = (i < EE) ? ei[EE + i] : (i - EE);
            atomicAdd(&h[d >> 9], 1);
        }
    }
    __syncthreads();
    lbase[t] = (t < NB && h[t]) ? atomicAdd(&bcursor[t], h[t]) : 0;
    __syncthreads();
    h[t] = 0;
    __syncthreads();
    #pragma unroll 4
    for (int j = 0; j < 32; ++j) {
        int i = base + j * 256 + t;
        if (i < ETOT) {
            int sv, dv;
            if (i < EE) { sv = ei[i]; dv = ei[EE + i]; }
            else        { sv = i - EE; dv = sv; }
            int bk = dv >> 9;
            int off = atomicAdd(&h[bk], 1);
            pairs[lbase[bk] + off] = make_uint2((uint_t)sv, (uint_t)dv);
        }
    }
}

__global__ __launch_bounds__(256) void bucket_build(const uint2* __restrict__ pairs,
                                                    const int* __restrict__ bbase,
                                                    int* __restrict__ rowptr,
                                                    int* __restrict__ csrc) {
    __shared__ int cnt[512];
    __shared__ int cur[512];
    int b = blockIdx.x;
    int t = threadIdx.x;
    int lo = b << 9;
    int nn = NN - lo; if (nn > 512) nn = 512;
    int e0 = bbase[b];
    int e1 = bbase[b + 1];
    cnt[t] = 0; cnt[t + 256] = 0;
    __syncthreads();
    for (int i = e0 + t; i < e1; i += 256)
        atomicAdd(&cnt[pairs[i].y - lo], 1);
    __syncthreads();
    int oc0 = cnt[t], oc1 = cnt[t + 256];
    // inclusive Hillis-Steele scan over 512 with 256 threads
    for (int off = 1; off < 512; off <<= 1) {
        int i0 = t, i1 = t + 256;
        int a0 = cnt[i0] + ((i0 >= off) ? cnt[i0 - off] : 0);
        int a1 = cnt[i1] + ((i1 >= off) ? cnt[i1 - off] : 0);
        __syncthreads();
        cnt[i0] = a0; cnt[i1] = a1;
        __syncthreads();
    }
    int ex0 = cnt[t] - oc0, ex1 = cnt[t + 256] - oc1;
    __syncthreads();
    cur[t] = e0 + ex0; cur[t + 256] = e0 + ex1;
    if (t < nn)       rowptr[lo + t] = e0 + ex0;
    if (t + 256 < nn) rowptr[lo + 256 + t] = e0 + ex1;
    __syncthreads();
    for (int i = e0 + t; i < e1; i += 256) {
        uint2 p = pairs[i];
        int pos = atomicAdd(&cur[p.y - lo], 1);
        csrc[pos] = (int)p.x;
    }
}

// ================= weight transpose + cast =================

__global__ void castw(const float* __restrict__ proj_w, const float* __restrict__ W,
                      ushort_t* __restrict__ pwT, ushort_t* __restrict__ WT) {
    int id = blockIdx.x * 256 + threadIdx.x;
    if (id < 32768) {
        int n = id >> 8, k = id & 255;
        pwT[id] = (ushort_t)f2bf(proj_w[k * 128 + n]);     // pwT[n][k], K=256
    } else if (id < 81920) {
        int id2 = id - 32768;
        int l = id2 >> 14, r = id2 & 16383;
        int n = r >> 7, k = r & 127;
        WT[id2] = (ushort_t)f2bf(W[l * 16384 + k * 128 + n]); // WT[l][n][k]
    }
}

// ================= bf16 MFMA GEMM: [M x K] @ [K x 128] =================
// A: fp32 or bf16 row-major. Bt: [128][K] bf16 (pre-transposed).
// Out: optional fp32 Cf (+bias+elu) and packed-bf16 Cb [M][128].

__global__ __launch_bounds__(256) void gemm_mfma(
    const void* __restrict__ Aptr, int a_fp32,
    const ushort_t* __restrict__ Bt, int K,
    float* __restrict__ Cf, const float* __restrict__ bias,
    ushort_t* __restrict__ Cb, int M)
{
    __shared__ uint4 smem[2304];                 // 36864 B
    ushort_t* As = (ushort_t*)smem;              // [128][72] bf16 (pad 8)
    ushort_t* Bs = As + 128 * 72;                // [128][72]

    int t = threadIdx.x;
    int row0 = blockIdx.x * 128;
    int lane = t & 63, wv = t >> 6;
    int wm = wv >> 1, wn = wv & 1;
    int lr = lane & 15, quad = lane >> 4;

    float4v acc[4][4] = {};

    for (int k0 = 0; k0 < K; k0 += 64) {
        if (a_fp32) {
            const float* A = (const float*)Aptr;
            #pragma unroll
            for (int j = 0; j < 8; ++j) {
                int idx = j * 256 + t;
                int row = idx >> 4;
                int c4 = (idx & 15) * 4;
                int gr = row0 + row;
                float4 v = make_float4(0.f, 0.f, 0.f, 0.f);
                if (gr < M) v = *(const float4*)(A + (size_t)gr * K + k0 + c4);
                uint2 u; u.x = pack2(v.x, v.y); u.y = pack2(v.z, v.w);
                *(uint2*)&As[row * 72 + c4] = u;
            }
        } else {
            const ushort_t* A = (const ushort_t*)Aptr;
            #pragma unroll
            for (int j = 0; j < 4; ++j) {
                int idx = j * 256 + t;
                int row = idx >> 3;
                int c8 = (idx & 7) * 8;
                int gr = row0 + row;
                uint4 v = make_uint4(0, 0, 0, 0);
                if (gr < M) v = *(const uint4*)(A + (size_t)gr * K + k0 + c8);
                *(uint4*)&As[row * 72 + c8] = v;
            }
        }
        #pragma unroll
        for (int j = 0; j < 4; ++j) {
            int idx = j * 256 + t;
            int row = idx >> 3;
            int c8 = (idx & 7) * 8;
            uint4 v = *(const uint4*)(Bt + (size_t)row * K + k0 + c8);
            *(uint4*)&Bs[row * 72 + c8] = v;
        }
        __syncthreads();

        const ushort_t* Ab = As + (wm * 64 + lr) * 72 + quad * 8;
        const ushort_t* Bb = Bs + (wn * 64 + lr) * 72 + quad * 8;
        #pragma unroll
        for (int ks = 0; ks < 64; ks += 32) {
            short8 a[4], b[4];
            #pragma unroll
            for (int ti = 0; ti < 4; ++ti) a[ti] = *(const short8*)(Ab + ti * 16 * 72 + ks);
            #pragma unroll
            for (int tj = 0; tj < 4; ++tj) b[tj] = *(const short8*)(Bb + tj * 16 * 72 + ks);
            #pragma unroll
            for (int ti = 0; ti < 4; ++ti)
                #pragma unroll
                for (int tj = 0; tj < 4; ++tj)
                    acc[ti][tj] = __builtin_amdgcn_mfma_f32_16x16x32_bf16(
                        a[ti], b[tj], acc[ti][tj], 0, 0, 0);
        }
        __syncthreads();
    }

    // epilogue: LDS bounce [32][132] fp32, coalesced global stores
    float* sc = (float*)smem;
    for (int ti = 0; ti < 4; ++ti) {
        #pragma unroll
        for (int tj = 0; tj < 4; ++tj) {
            #pragma unroll
            for (int r = 0; r < 4; ++r) {
                int rloc = wm * 16 + quad * 4 + r;
                int col = wn * 64 + tj * 16 + lr;
                sc[rloc * 132 + col] = acc[ti][tj][r];
            }
        }
        __syncthreads();
        #pragma unroll
        for (int j = 0; j < 4; ++j) {
            int idx = j * 256 + t;
            int row = idx >> 5;
            int c4 = (idx & 31) * 4;
            float4 v = *(const float4*)&sc[row * 132 + c4];
            int gr = row0 + (row >> 4) * 64 + ti * 16 + (row & 15);
            if (gr < M) {
                if (Cf) {
                    float4 bv = *(const float4*)(bias + c4);
                    v.x += bv.x; v.y += bv.y; v.z += bv.z; v.w += bv.w;
                    v.x = v.x > 0.f ? v.x : __expf(v.x) - 1.f;
                    v.y = v.y > 0.f ? v.y : __expf(v.y) - 1.f;
                    v.z = v.z > 0.f ? v.z : __expf(v.z) - 1.f;
                    v.w = v.w > 0.f ? v.w : __expf(v.w) - 1.f;
                    *(float4*)(Cf + (size_t)gr * 128 + c4) = v;
                }
                uint2 u; u.x = pack2(v.x, v.y); u.y = pack2(v.z, v.w);
                *(uint2*)(Cb + (size_t)gr * 128 + c4) = u;
            }
        }
        __syncthreads();
    }
}

// ================= attention logits (bf16 h2b) =================

__global__ void compute_al(const uint_t* __restrict__ h2b, const float* __restrict__ a_s,
                           const float* __restrict__ a_d, float* __restrict__ al_s,
                           float* __restrict__ al_d) {
    int i = blockIdx.x * blockDim.x + threadIdx.x;
    if (i >= NN * HEADS) return;
    int hh = i & 7, nd = i >> 3;
    const uint_t* hp = h2b + (size_t)nd * 64 + hh * 8;
    uint4 u0 = *(const uint4*)hp;
    uint4 u1 = *(const uint4*)(hp + 4);
    uint_t uu[8] = {u0.x, u0.y, u0.z, u0.w, u1.x, u1.y, u1.z, u1.w};
    const float* sp = a_s + hh * CH;
    const float* dp = a_d + hh * CH;
    float s1 = 0.f, s2 = 0.f;
    #pragma unroll
    for (int j = 0; j < 8; ++j) {
        float lo = __uint_as_float(uu[j] << 16);
        float hi = __uint_as_float(uu[j] & 0xffff0000u);
        s1 += lo * sp[2 * j] + hi * sp[2 * j + 1];
        s2 += lo * dp[2 * j] + hi * dp[2 * j + 1];
    }
    al_s[i] = s1;
    al_d[i] = s2;
}

// ================= GAT aggregation: wave per dst, bf16 gather, 8x unroll =====

__global__ __launch_bounds__(256) void gat_agg(
    const int* __restrict__ rowptr, const int* __restrict__ csrc,
    const uint_t* __restrict__ h2b, const float* __restrict__ al_s,
    const float* __restrict__ al_d, const float* __restrict__ bias,
    float* __restrict__ out)
{
    int wv = (blockIdx.x * blockDim.x + threadIdx.x) >> 6;
    int lane = threadIdx.x & 63;
    if (wv >= NN) return;
    int e0 = rowptr[wv], e1 = rowptr[wv + 1];
    int head = lane >> 3;
    int ch = lane * 2;
    float ald = al_d[wv * HEADS + head];
    float acc0 = 0.f, acc1 = 0.f, denom = 0.f;

    int e = e0;
    for (; e + 8 <= e1; e += 8) {
        int ss[8]; float aa[8]; uint_t pp[8];
        #pragma unroll
        for (int k = 0; k < 8; ++k) ss[k] = csrc[e + k];
        #pragma unroll
        for (int k = 0; k < 8; ++k) aa[k] = al_s[ss[k] * HEADS + head];
        #pragma unroll
        for (int k = 0; k < 8; ++k) pp[k] = h2b[(size_t)ss[k] * 64 + lane];
        #pragma unroll
        for (int k = 0; k < 8; ++k) {
            float x = aa[k] + ald;
            x = x > 0.f ? x : NEG_SLOPE * x;
            float w = __expf(x);
            acc0 += w * __uint_as_float(pp[k] << 16);
            acc1 += w * __uint_as_float(pp[k] & 0xffff0000u);
            denom += w;
        }
    }
    for (; e < e1; ++e) {
        int s = csrc[e];
        float a = al_s[s * HEADS + head];
        uint_t p = h2b[(size_t)s * 64 + lane];
        float x = a + ald; x = x > 0.f ? x : NEG_SLOPE * x;
        float w = __expf(x);
        acc0 += w * __uint_as_float(p << 16);
        acc1 += w * __uint_as_float(p & 0xffff0000u);
        denom += w;
    }
    float inv = 1.0f / (denom + 1e-16f);
    out[(size_t)wv * HID + ch]     = acc0 * inv + bias[ch];
    out[(size_t)wv * HID + ch + 1] = acc1 * inv + bias[ch + 1];
}

// ================= batchnorm =================

__global__ void bn_stats(const float* __restrict__ a, float* stats) {
    int t = threadIdx.x;  // 128
    float s = 0.f, q = 0.f;
    for (int r = blockIdx.x; r < NN; r += gridDim.x) {
        float v = a[(size_t)r * HID + t];
        s += v;
        q += v * v;
    }
    atomicAdd(&stats[t], s);
    atomicAdd(&stats[HID + t], q);
}

__global__ void bn_apply(const float* __restrict__ a, const float* __restrict__ stats,
                         const float* __restrict__ g, const float* __restrict__ be,
                         float* __restrict__ h, ushort_t* __restrict__ hb) {
    int i = blockIdx.x * blockDim.x + threadIdx.x;
    if (i >= NN * 32) return;
    int c4 = (i & 31) * 4;
    int nd = i >> 5;
    float4 v = *(const float4*)(a + (size_t)nd * HID + c4);
    float4 r = *(const float4*)(h + (size_t)nd * HID + c4);
    float vv[4] = {v.x, v.y, v.z, v.w};
    float rr[4] = {r.x, r.y, r.z, r.w};
    float o[4];
    #pragma unroll
    for (int j = 0; j < 4; ++j) {
        int c = c4 + j;
        float mu = stats[c] * (1.0f / NN);
        float var = stats[HID + c] * (1.0f / NN) - mu * mu;
        float rs = rsqrtf(var + EPS_BN);
        float x = (vv[j] - mu) * rs * g[c] + be[c];
        x = x > 0.f ? x : __expf(x) - 1.f;
        o[j] = x + rr[j];
    }
    *(float4*)(h + (size_t)nd * HID + c4) = make_float4(o[0], o[1], o[2], o[3]);
    uint2 u; u.x = pack2(o[0], o[1]); u.y = pack2(o[2], o[3]);
    *(uint2*)(hb + (size_t)nd * HID + c4) = u;
}

// ================= final FC =================

__global__ __launch_bounds__(256) void fc_kernel(
    const float* __restrict__ h, const float* __restrict__ w,
    const float* __restrict__ b, float* __restrict__ out)
{
    int wv = (blockIdx.x * blockDim.x + threadIdx.x) >> 6;
    int lane = threadIdx.x & 63;
    if (wv >= NN) return;
    float2 hv = *(const float2*)(h + (size_t)wv * HID + lane * 2);
    float2 wl = *(const float2*)(w + lane * 2);
    float acc = hv.x * wl.x + hv.y * wl.y;
    #pragma unroll
    for (int off = 32; off > 0; off >>= 1)
        acc += __shfl_down(acc, off, 64);
    if (lane == 0) out[wv] = acc + b[0];
}

// ================= launch =================

extern "C" void kernel_launch(void* const* d_in, const int* in_sizes, int n_in,
                              void* d_out, int out_size, void* d_ws, size_t ws_size,
                              hipStream_t stream) {
    const float* x       = (const float*)d_in[0];
    const int*   ei      = (const int*)  d_in[1];
    const float* proj_w  = (const float*)d_in[2];
    const float* proj_b  = (const float*)d_in[3];
    const float* W       = (const float*)d_in[4];
    const float* att_src = (const float*)d_in[5];
    const float* att_dst = (const float*)d_in[6];
    const float* conv_b  = (const float*)d_in[7];
    const float* bn_g    = (const float*)d_in[8];
    const float* bn_b    = (const float*)d_in[9];
    const float* fc_w    = (const float*)d_in[10];
    const float* fc_b    = (const float*)d_in[11];
    float* out = (float*)d_out;

    char* p = (char*)d_ws;
    float*    h    = (float*)p;    p += (size_t)NN * HID * 4;        // 51.2 MB
    ushort_t* hb   = (ushort_t*)p; p += (size_t)NN * HID * 2;        // 25.6 MB
    ushort_t* h2b  = (ushort_t*)p; p += (size_t)NN * HID * 2;        // 25.6 MB
    float*    agg  = (float*)p;    p += (size_t)NN * HID * 4;        // 51.2 MB
    uint2*    pairs = (uint2*)agg;                                    // alias (dead before agg use)
    float*    al_s = (float*)p;    p += (size_t)NN * HEADS * 4;
    float*    al_d = (float*)p;    p += (size_t)NN * HEADS * 4;
    int* rowptr    = (int*)p;      p += ((size_t)(NN + 1) * 4 + 255) & ~255ull;
    int* csrc      = (int*)p;      p += (size_t)ETOT * 4;
    int* bcnt      = (int*)p;      p += 1024;
    int* bbase     = (int*)p;      p += 1024;
    int* bcursor   = (int*)p;      p += 1024;
    ushort_t* pwT  = (ushort_t*)p; p += 128 * 256 * 2;
    ushort_t* WT   = (ushort_t*)p; p += 3 * 128 * 128 * 2;
    float* stats   = (float*)p;    p += 1024;
    (void)ws_size; (void)n_in; (void)in_sizes; (void)out_size;

    // --- weights cast/transpose ---
    castw<<<320, 256, 0, stream>>>(proj_w, W, pwT, WT);

    // --- initial projection: h = elu(x @ proj_w + b), hb = bf16(h) ---
    gemm_mfma<<<(NN + 127) / 128, 256, 0, stream>>>(x, 1, pwT, 256, h, proj_b, hb, NN);

    // --- CSR build (bucketed counting sort); pairs alias agg, done before layers ---
    hipMemsetAsync(bcnt, 0, NB * 4, stream);
    bucket_hist<<<NBLK_A, 256, 0, stream>>>(ei, bcnt);
    bucket_scan<<<1, 256, 0, stream>>>(bcnt, bbase, bcursor, rowptr);
    bucket_scatter<<<NBLK_A, 256, 0, stream>>>(ei, bcursor, pairs);
    bucket_build<<<NB, 256, 0, stream>>>(pairs, bbase, rowptr, csrc);

    for (int l = 0; l < 3; ++l) {
        const ushort_t* WTl = WT + (size_t)l * 128 * 128;
        const float* asl = att_src + (size_t)l * HEADS * CH;
        const float* adl = att_dst + (size_t)l * HEADS * CH;
        const float* cbl = conv_b + (size_t)l * HID;
        const float* gl  = bn_g + (size_t)l * HID;
        const float* bl  = bn_b + (size_t)l * HID;

        gemm_mfma<<<(NN + 127) / 128, 256, 0, stream>>>(hb, 0, WTl, 128, nullptr, nullptr, h2b, NN);
        compute_al<<<(NN * HEADS + 255) / 256, 256, 0, stream>>>((const uint_t*)h2b, asl, adl, al_s, al_d);
        gat_agg<<<(NN + 3) / 4, 256, 0, stream>>>(rowptr, csrc, (const uint_t*)h2b, al_s, al_d, cbl, agg);
        hipMemsetAsync(stats, 0, 256 * 4, stream);
        bn_stats<<<512, 128, 0, stream>>>(agg, stats);
        bn_apply<<<(NN * 32 + 255) / 256, 256, 0, stream>>>(agg, stats, gl, bl, h, hb);
    }

    fc_kernel<<<(NN + 3) / 4, 256, 0, stream>>>(h, fc_w, fc_b, out);
}

// Round 5
// 845.363 us; speedup vs baseline: 1.7396x; 1.0720x over previous
//
#include <hip/hip_runtime.h>
#include <hip/hip_bf16.h>

#define NN 100000
#define EE 1600000
#define ETOT (NN + EE)
#define HID 128
#define HEADS 8
#define CH 16
#define EPS_BN 1e-5f
#define NEG_SLOPE 0.2f
#define NB 196            // buckets of 512 dst nodes
#define NBLK_A 208        // ceil(ETOT / 8192)

typedef unsigned short ushort_t;
typedef unsigned int uint_t;
typedef __attribute__((ext_vector_type(8))) short short8;
typedef __attribute__((ext_vector_type(4))) float float4v;

__device__ inline uint_t f2bf(float x) {
    __hip_bfloat16 b = __float2bfloat16(x);
    return (uint_t)*reinterpret_cast<unsigned short*>(&b);
}
__device__ inline uint_t pack2(float lo, float hi) {
    return f2bf(lo) | (f2bf(hi) << 16);
}
__device__ inline float bf_lo(uint_t u) { return __uint_as_float(u << 16); }
__device__ inline float bf_hi(uint_t u) { return __uint_as_float(u & 0xffff0000u); }

// ================= CSR build: bucketed counting sort =================
// pass 1: per-block histogram; reserve per-block base in each bucket via atomic.
__global__ __launch_bounds__(256) void bucket_hist(const int* __restrict__ ei,
                                                   int* bcnt, int* lbase) {
    __shared__ int h[256];
    int t = threadIdx.x;
    h[t] = 0;
    __syncthreads();
    int base = blockIdx.x * 8192;
    #pragma unroll 4
    for (int j = 0; j < 32; ++j) {
        int i = base + j * 256 + t;
        if (i < ETOT) {
            int d = (i < EE) ? ei[EE + i] : (i - EE);
            atomicAdd(&h[d >> 9], 1);
        }
    }
    __syncthreads();
    // NOTE: guard t < NB — stride of lbase is NB, writing t>=NB would race
    // with the next block's [0,NB) range (round-4 crash root cause).
    if (t < NB) {
        int v = h[t];
        lbase[blockIdx.x * NB + t] = v ? atomicAdd(&bcnt[t], v) : 0;
    }
}

__global__ void bucket_scan(const int* __restrict__ bcnt, int* bbase, int* rowptr) {
    __shared__ int s[256];
    int t = threadIdx.x;
    int orig = (t < NB) ? bcnt[t] : 0;
    s[t] = orig;
    __syncthreads();
    for (int off = 1; off < 256; off <<= 1) {
        int add = (t >= off) ? s[t - off] : 0;
        __syncthreads();
        s[t] += add;
        __syncthreads();
    }
    if (t < NB) bbase[t] = s[t] - orig;
    if (t == 0) { bbase[NB] = ETOT; rowptr[NN] = ETOT; }
}

// pass 2: scatter packed (src<<9 | dst&511) into per-bucket contiguous runs.
__global__ __launch_bounds__(256) void bucket_scatter(const int* __restrict__ ei,
                                                      const int* __restrict__ bbase,
                                                      const int* __restrict__ lbase,
                                                      uint_t* __restrict__ pairs) {
    __shared__ int sbase[256];
    __shared__ int h[256];
    int t = threadIdx.x;
    sbase[t] = (t < NB) ? (bbase[t] + lbase[blockIdx.x * NB + t]) : 0;
    h[t] = 0;
    __syncthreads();
    int base = blockIdx.x * 8192;
    #pragma unroll 4
    for (int j = 0; j < 32; ++j) {
        int i = base + j * 256 + t;
        if (i < ETOT) {
            int sv, dv;
            if (i < EE) { sv = ei[i]; dv = ei[EE + i]; }
            else        { sv = i - EE; dv = sv; }
            int bk = dv >> 9;
            int off = atomicAdd(&h[bk], 1);
            pairs[sbase[bk] + off] = ((uint_t)sv << 9) | (uint_t)(dv & 511);
        }
    }
}

__global__ __launch_bounds__(256) void bucket_build(const uint_t* __restrict__ pairs,
                                                    const int* __restrict__ bbase,
                                                    int* __restrict__ rowptr,
                                                    int* __restrict__ csrc) {
    __shared__ int cnt[512];
    __shared__ int cur[512];
    int b = blockIdx.x;
    int t = threadIdx.x;
    int lo = b << 9;
    int nn = NN - lo; if (nn > 512) nn = 512;
    int e0 = bbase[b];
    int e1 = bbase[b + 1];
    cnt[t] = 0; cnt[t + 256] = 0;
    __syncthreads();
    for (int i = e0 + t; i < e1; i += 256)
        atomicAdd(&cnt[pairs[i] & 511], 1);
    __syncthreads();
    int oc0 = cnt[t], oc1 = cnt[t + 256];
    for (int off = 1; off < 512; off <<= 1) {
        int i0 = t, i1 = t + 256;
        int a0 = cnt[i0] + ((i0 >= off) ? cnt[i0 - off] : 0);
        int a1 = cnt[i1] + ((i1 >= off) ? cnt[i1 - off] : 0);
        __syncthreads();
        cnt[i0] = a0; cnt[i1] = a1;
        __syncthreads();
    }
    int ex0 = cnt[t] - oc0, ex1 = cnt[t + 256] - oc1;
    __syncthreads();
    cur[t] = e0 + ex0; cur[t + 256] = e0 + ex1;
    if (t < nn)       rowptr[lo + t] = e0 + ex0;
    if (t + 256 < nn) rowptr[lo + 256 + t] = e0 + ex1;
    __syncthreads();
    for (int i = e0 + t; i < e1; i += 256) {
        uint_t p = pairs[i];
        int pos = atomicAdd(&cur[p & 511], 1);
        csrc[pos] = (int)(p >> 9);
    }
}

// ================= weight transpose + cast =================

__global__ void castw(const float* __restrict__ proj_w, const float* __restrict__ W,
                      ushort_t* __restrict__ pwT, ushort_t* __restrict__ WT) {
    int id = blockIdx.x * 256 + threadIdx.x;
    if (id < 32768) {
        int n = id >> 8, k = id & 255;
        pwT[id] = (ushort_t)f2bf(proj_w[k * 128 + n]);     // pwT[n][k], K=256
    } else if (id < 81920) {
        int id2 = id - 32768;
        int l = id2 >> 14, r = id2 & 16383;
        int n = r >> 7, k = r & 127;
        WT[id2] = (ushort_t)f2bf(W[l * 16384 + k * 128 + n]); // WT[l][n][k]
    }
}

// ================= bf16 MFMA GEMM: [M x K] @ [K x 128] =================
// A: fp32 or bf16 row-major. Bt: [128][K] bf16 (pre-transposed).
// Out: packed-bf16 Cb [M][128] (optionally +bias+elu), optional al_s/al_d
// (attention logits, computed from fp32 accumulators in LDS).

__global__ __launch_bounds__(256) void gemm_mfma(
    const void* __restrict__ Aptr, int a_fp32,
    const ushort_t* __restrict__ Bt, int K,
    const float* __restrict__ bias, ushort_t* __restrict__ Cb,
    const float* __restrict__ a_src, const float* __restrict__ a_dst,
    float* __restrict__ al_s, float* __restrict__ al_d, int M)
{
    __shared__ uint4 smem[2304];                 // 36864 B
    ushort_t* As = (ushort_t*)smem;              // [128][72] bf16 (pad 8)
    ushort_t* Bs = As + 128 * 72;                // [128][72]

    int t = threadIdx.x;
    int row0 = blockIdx.x * 128;
    int lane = t & 63, wv = t >> 6;
    int wm = wv >> 1, wn = wv & 1;
    int lr = lane & 15, quad = lane >> 4;

    float4v acc[4][4] = {};

    for (int k0 = 0; k0 < K; k0 += 64) {
        if (a_fp32) {
            const float* A = (const float*)Aptr;
            #pragma unroll
            for (int j = 0; j < 8; ++j) {
                int idx = j * 256 + t;
                int row = idx >> 4;
                int c4 = (idx & 15) * 4;
                int gr = row0 + row;
                float4 v = make_float4(0.f, 0.f, 0.f, 0.f);
                if (gr < M) v = *(const float4*)(A + (size_t)gr * K + k0 + c4);
                uint2 u; u.x = pack2(v.x, v.y); u.y = pack2(v.z, v.w);
                *(uint2*)&As[row * 72 + c4] = u;
            }
        } else {
            const ushort_t* A = (const ushort_t*)Aptr;
            #pragma unroll
            for (int j = 0; j < 4; ++j) {
                int idx = j * 256 + t;
                int row = idx >> 3;
                int c8 = (idx & 7) * 8;
                int gr = row0 + row;
                uint4 v = make_uint4(0, 0, 0, 0);
                if (gr < M) v = *(const uint4*)(A + (size_t)gr * K + k0 + c8);
                *(uint4*)&As[row * 72 + c8] = v;
            }
        }
        #pragma unroll
        for (int j = 0; j < 4; ++j) {
            int idx = j * 256 + t;
            int row = idx >> 3;
            int c8 = (idx & 7) * 8;
            uint4 v = *(const uint4*)(Bt + (size_t)row * K + k0 + c8);
            *(uint4*)&Bs[row * 72 + c8] = v;
        }
        __syncthreads();

        const ushort_t* Ab = As + (wm * 64 + lr) * 72 + quad * 8;
        const ushort_t* Bb = Bs + (wn * 64 + lr) * 72 + quad * 8;
        #pragma unroll
        for (int ks = 0; ks < 64; ks += 32) {
            short8 a[4], b[4];
            #pragma unroll
            for (int ti = 0; ti < 4; ++ti) a[ti] = *(const short8*)(Ab + ti * 16 * 72 + ks);
            #pragma unroll
            for (int tj = 0; tj < 4; ++tj) b[tj] = *(const short8*)(Bb + tj * 16 * 72 + ks);
            #pragma unroll
            for (int ti = 0; ti < 4; ++ti)
                #pragma unroll
                for (int tj = 0; tj < 4; ++tj)
                    acc[ti][tj] = __builtin_amdgcn_mfma_f32_16x16x32_bf16(
                        a[ti], b[tj], acc[ti][tj], 0, 0, 0);
        }
        __syncthreads();
    }

    // epilogue: LDS bounce [32][132] fp32; coalesced bf16 stores; fused al logits
    float* sc = (float*)smem;
    for (int ti = 0; ti < 4; ++ti) {
        #pragma unroll
        for (int tj = 0; tj < 4; ++tj) {
            #pragma unroll
            for (int r = 0; r < 4; ++r) {
                int rloc = wm * 16 + quad * 4 + r;
                int col = wn * 64 + tj * 16 + lr;
                sc[rloc * 132 + col] = acc[ti][tj][r];
            }
        }
        __syncthreads();
        #pragma unroll
        for (int j = 0; j < 4; ++j) {
            int idx = j * 256 + t;
            int row = idx >> 5;
            int c4 = (idx & 31) * 4;
            float4 v = *(const float4*)&sc[row * 132 + c4];
            int gr = row0 + (row >> 4) * 64 + ti * 16 + (row & 15);
            if (gr < M) {
                if (bias) {
                    float4 bv = *(const float4*)(bias + c4);
                    v.x += bv.x; v.y += bv.y; v.z += bv.z; v.w += bv.w;
                    v.x = v.x > 0.f ? v.x : __expf(v.x) - 1.f;
                    v.y = v.y > 0.f ? v.y : __expf(v.y) - 1.f;
                    v.z = v.z > 0.f ? v.z : __expf(v.z) - 1.f;
                    v.w = v.w > 0.f ? v.w : __expf(v.w) - 1.f;
                }
                uint2 u; u.x = pack2(v.x, v.y); u.y = pack2(v.z, v.w);
                *(uint2*)(Cb + (size_t)gr * 128 + c4) = u;
            }
        }
        if (al_s) {
            int row = t & 31, head = t >> 5;
            int gr = row0 + (row >> 4) * 64 + ti * 16 + (row & 15);
            if (gr < M) {
                const float* rp = &sc[row * 132 + head * 16];
                const float* spv = a_src + head * 16;
                const float* dpv = a_dst + head * 16;
                float s1 = 0.f, s2 = 0.f;
                #pragma unroll
                for (int c = 0; c < 16; ++c) {
                    float hv = rp[c];
                    s1 += hv * spv[c];
                    s2 += hv * dpv[c];
                }
                al_s[gr * 8 + head] = s1;
                al_d[gr * 8 + head] = s2;
            }
        }
        __syncthreads();
    }
}

// ================= GAT aggregation: wave per dst, bf16 gather, 8x unroll =====

__global__ __launch_bounds__(256) void gat_agg(
    const int* __restrict__ rowptr, const int* __restrict__ csrc,
    const uint_t* __restrict__ h2b, const float* __restrict__ al_s,
    const float* __restrict__ al_d, const float* __restrict__ bias,
    uint_t* __restrict__ outb)
{
    int wv = (blockIdx.x * blockDim.x + threadIdx.x) >> 6;
    int lane = threadIdx.x & 63;
    if (wv >= NN) return;
    int e0 = rowptr[wv], e1 = rowptr[wv + 1];
    int head = lane >> 3;
    int ch = lane * 2;
    float ald = al_d[wv * HEADS + head];
    float acc0 = 0.f, acc1 = 0.f, denom = 0.f;

    int e = e0;
    for (; e + 8 <= e1; e += 8) {
        int ss[8]; float aa[8]; uint_t pp[8];
        #pragma unroll
        for (int k = 0; k < 8; ++k) ss[k] = csrc[e + k];
        #pragma unroll
        for (int k = 0; k < 8; ++k) aa[k] = al_s[ss[k] * HEADS + head];
        #pragma unroll
        for (int k = 0; k < 8; ++k) pp[k] = h2b[(size_t)ss[k] * 64 + lane];
        #pragma unroll
        for (int k = 0; k < 8; ++k) {
            float x = aa[k] + ald;
            x = fmaxf(x, NEG_SLOPE * x);
            float w = __expf(x);
            acc0 += w * bf_lo(pp[k]);
            acc1 += w * bf_hi(pp[k]);
            denom += w;
        }
    }
    for (; e < e1; ++e) {
        int s = csrc[e];
        float a = al_s[s * HEADS + head];
        uint_t p = h2b[(size_t)s * 64 + lane];
        float x = a + ald;
        x = fmaxf(x, NEG_SLOPE * x);
        float w = __expf(x);
        acc0 += w * bf_lo(p);
        acc1 += w * bf_hi(p);
        denom += w;
    }
    float inv = 1.0f / (denom + 1e-16f);
    outb[(size_t)wv * 64 + lane] = pack2(acc0 * inv + bias[ch], acc1 * inv + bias[ch + 1]);
}

// ================= batchnorm =================

__global__ void bn_stats(const uint_t* __restrict__ ab, float* stats) {
    int t = threadIdx.x;  // 128: channel t
    int u_idx = t >> 1, hi = t & 1;
    float s = 0.f, q = 0.f;
    for (int r = blockIdx.x; r < NN; r += gridDim.x) {
        uint_t u = ab[(size_t)r * 64 + u_idx];
        float v = hi ? bf_hi(u) : bf_lo(u);
        s += v;
        q += v * v;
    }
    atomicAdd(&stats[t], s);
    atomicAdd(&stats[HID + t], q);
}

__global__ void bn_apply(const uint_t* __restrict__ ab, const float* __restrict__ stats,
                         const float* __restrict__ g, const float* __restrict__ be,
                         uint_t* __restrict__ hb) {
    int i = blockIdx.x * blockDim.x + threadIdx.x;
    if (i >= NN * 32) return;
    int c4 = (i & 31) * 4;      // channel base (4 channels = 2 uints)
    int nd = i >> 5;
    uint2 av = *(const uint2*)(ab + (size_t)nd * 64 + (c4 >> 1));
    uint2 rv = *(const uint2*)(hb + (size_t)nd * 64 + (c4 >> 1));
    float vv[4] = {bf_lo(av.x), bf_hi(av.x), bf_lo(av.y), bf_hi(av.y)};
    float rr[4] = {bf_lo(rv.x), bf_hi(rv.x), bf_lo(rv.y), bf_hi(rv.y)};
    float o[4];
    #pragma unroll
    for (int j = 0; j < 4; ++j) {
        int c = c4 + j;
        float mu = stats[c] * (1.0f / NN);
        float var = stats[HID + c] * (1.0f / NN) - mu * mu;
        float rs = rsqrtf(var + EPS_BN);
        float x = (vv[j] - mu) * rs * g[c] + be[c];
        x = x > 0.f ? x : __expf(x) - 1.f;
        o[j] = x + rr[j];
    }
    uint2 u; u.x = pack2(o[0], o[1]); u.y = pack2(o[2], o[3]);
    *(uint2*)(hb + (size_t)nd * 64 + (c4 >> 1)) = u;
}

// ================= final FC =================

__global__ __launch_bounds__(256) void fc_kernel(
    const uint_t* __restrict__ hb, const float* __restrict__ w,
    const float* __restrict__ b, float* __restrict__ out)
{
    int wv = (blockIdx.x * blockDim.x + threadIdx.x) >> 6;
    int lane = threadIdx.x & 63;
    if (wv >= NN) return;
    uint_t u = hb[(size_t)wv * 64 + lane];
    float2 wl = *(const float2*)(w + lane * 2);
    float acc = bf_lo(u) * wl.x + bf_hi(u) * wl.y;
    #pragma unroll
    for (int off = 32; off > 0; off >>= 1)
        acc += __shfl_down(acc, off, 64);
    if (lane == 0) out[wv] = acc + b[0];
}

// ================= launch =================

extern "C" void kernel_launch(void* const* d_in, const int* in_sizes, int n_in,
                              void* d_out, int out_size, void* d_ws, size_t ws_size,
                              hipStream_t stream) {
    const float* x       = (const float*)d_in[0];
    const int*   ei      = (const int*)  d_in[1];
    const float* proj_w  = (const float*)d_in[2];
    const float* proj_b  = (const float*)d_in[3];
    const float* W       = (const float*)d_in[4];
    const float* att_src = (const float*)d_in[5];
    const float* att_dst = (const float*)d_in[6];
    const float* conv_b  = (const float*)d_in[7];
    const float* bn_g    = (const float*)d_in[8];
    const float* bn_b    = (const float*)d_in[9];
    const float* fc_w    = (const float*)d_in[10];
    const float* fc_b    = (const float*)d_in[11];
    float* out = (float*)d_out;

    char* p = (char*)d_ws;
    uint_t*   hb   = (uint_t*)p;   p += (size_t)NN * 64 * 4;         // 25.6 MB (bf16x2)
    uint_t*   h2b  = (uint_t*)p;   p += (size_t)NN * 64 * 4;         // 25.6 MB
    uint_t*   aggb = (uint_t*)p;   p += (size_t)NN * 64 * 4;         // 25.6 MB
    uint_t*   pairs = (uint_t*)aggb;                                  // alias (dead early)
    float*    al_s = (float*)p;    p += (size_t)NN * HEADS * 4;
    float*    al_d = (float*)p;    p += (size_t)NN * HEADS * 4;
    int* rowptr    = (int*)p;      p += ((size_t)(NN + 1) * 4 + 255) & ~255ull;
    int* csrc      = (int*)p;      p += (size_t)ETOT * 4;
    int* bcnt      = (int*)p;      p += 1024;                        // memset with stats
    float* stats3  = (float*)p;    p += 3 * 1024;                    // 3 layers x 256 fp32
    int* bbase     = (int*)p;      p += 1024;
    int* lbase     = (int*)p;      p += (size_t)NBLK_A * NB * 4 + 256;
    ushort_t* pwT  = (ushort_t*)p; p += 128 * 256 * 2;
    ushort_t* WT   = (ushort_t*)p; p += 3 * 128 * 128 * 2;
    (void)ws_size; (void)n_in; (void)in_sizes; (void)out_size;

    // zero bcnt + stats (adjacent) in one memset
    hipMemsetAsync(bcnt, 0, 4096, stream);

    // --- weights cast/transpose ---
    castw<<<320, 256, 0, stream>>>(proj_w, W, pwT, WT);

    // --- initial projection: hb = bf16(elu(x @ proj_w + b)) ---
    gemm_mfma<<<(NN + 127) / 128, 256, 0, stream>>>(
        x, 1, pwT, 256, proj_b, (ushort_t*)hb, nullptr, nullptr, nullptr, nullptr, NN);

    // --- CSR build (bucketed counting sort); pairs alias aggb ---
    bucket_hist<<<NBLK_A, 256, 0, stream>>>(ei, bcnt, (int*)lbase);
    bucket_scan<<<1, 256, 0, stream>>>(bcnt, bbase, rowptr);
    bucket_scatter<<<NBLK_A, 256, 0, stream>>>(ei, bbase, (const int*)lbase, pairs);
    bucket_build<<<NB, 256, 0, stream>>>(pairs, bbase, rowptr, csrc);

    for (int l = 0; l < 3; ++l) {
        const ushort_t* WTl = WT + (size_t)l * 128 * 128;
        const float* asl = att_src + (size_t)l * HEADS * CH;
        const float* adl = att_dst + (size_t)l * HEADS * CH;
        const float* cbl = conv_b + (size_t)l * HID;
        const float* gl  = bn_g + (size_t)l * HID;
        const float* bl  = bn_b + (size_t)l * HID;
        float* stl = stats3 + l * 256;

        gemm_mfma<<<(NN + 127) / 128, 256, 0, stream>>>(
            hb, 0, WTl, 128, nullptr, (ushort_t*)h2b, asl, adl, al_s, al_d, NN);
        gat_agg<<<(NN + 3) / 4, 256, 0, stream>>>(rowptr, csrc, h2b, al_s, al_d, cbl, aggb);
        bn_stats<<<512, 128, 0, stream>>>(aggb, stl);
        bn_apply<<<(NN * 32 + 255) / 256, 256, 0, stream>>>(aggb, stl, gl, bl, hb);
    }

    fc_kernel<<<(NN + 3) / 4, 256, 0, stream>>>(hb, fc_w, fc_b, out);
}

// Round 6
// 836.668 us; speedup vs baseline: 1.7577x; 1.0104x over previous
//
#include <hip/hip_runtime.h>
#include <hip/hip_bf16.h>

#define NN 100000
#define EE 1600000
#define ETOT (NN + EE)
#define HID 128
#define HEADS 8
#define CH 16
#define EPS_BN 1e-5f
#define NEG_SLOPE 0.2f
#define NB 196            // buckets of 512 dst nodes
#define NBLK_A 208        // ceil(ETOT / 8192)

typedef unsigned short ushort_t;
typedef unsigned int uint_t;
typedef __attribute__((ext_vector_type(8))) short short8;
typedef __attribute__((ext_vector_type(4))) float float4v;

__device__ inline uint_t f2bf(float x) {
    __hip_bfloat16 b = __float2bfloat16(x);
    return (uint_t)*reinterpret_cast<unsigned short*>(&b);
}
__device__ inline uint_t pack2(float lo, float hi) {
    return f2bf(lo) | (f2bf(hi) << 16);
}
__device__ inline float bf_lo(uint_t u) { return __uint_as_float(u << 16); }
__device__ inline float bf_hi(uint_t u) { return __uint_as_float(u & 0xffff0000u); }

// ================= CSR build: bucketed counting sort =================
// pass 1: per-block histogram; reserve per-block base in each bucket via atomic.
__global__ __launch_bounds__(256) void bucket_hist(const int* __restrict__ ei,
                                                   int* bcnt, int* lbase) {
    __shared__ int h[256];
    int t = threadIdx.x;
    h[t] = 0;
    __syncthreads();
    int base = blockIdx.x * 8192;
    #pragma unroll 4
    for (int j = 0; j < 32; ++j) {
        int i = base + j * 256 + t;
        if (i < ETOT) {
            int d = (i < EE) ? ei[EE + i] : (i - EE);
            atomicAdd(&h[d >> 9], 1);
        }
    }
    __syncthreads();
    // guard t < NB: lbase stride is NB (round-4 crash root cause)
    if (t < NB) {
        int v = h[t];
        lbase[blockIdx.x * NB + t] = v ? atomicAdd(&bcnt[t], v) : 0;
    }
}

__global__ void bucket_scan(const int* __restrict__ bcnt, int* bbase, int* rowptr) {
    __shared__ int s[256];
    int t = threadIdx.x;
    int orig = (t < NB) ? bcnt[t] : 0;
    s[t] = orig;
    __syncthreads();
    for (int off = 1; off < 256; off <<= 1) {
        int add = (t >= off) ? s[t - off] : 0;
        __syncthreads();
        s[t] += add;
        __syncthreads();
    }
    if (t < NB) bbase[t] = s[t] - orig;
    if (t == 0) { bbase[NB] = ETOT; rowptr[NN] = ETOT; }
}

// pass 2: LDS-staged counting sort per block; linear coalesced write of
// packed (src<<9 | dst&511) into per-bucket contiguous runs.
__global__ __launch_bounds__(256) void bucket_scatter(const int* __restrict__ ei,
                                                      const int* __restrict__ bbase,
                                                      const int* __restrict__ lbase,
                                                      uint_t* __restrict__ pairs) {
    __shared__ uint_t spair[8192];          // 32 KB: edges sorted by bucket
    __shared__ unsigned char sbk[8192];     // 8 KB: bucket id per sorted slot
    __shared__ int h[256];                  // histogram -> cursor
    __shared__ int lscan[256];              // exclusive scan
    __shared__ int sbase[256];
    int t = threadIdx.x;
    int base = blockIdx.x * 8192;
    int nloc = ETOT - base; if (nloc > 8192) nloc = 8192;
    sbase[t] = (t < NB) ? (bbase[t] + lbase[blockIdx.x * NB + t]) : 0;
    h[t] = 0;
    __syncthreads();
    // pass A: local histogram
    #pragma unroll 4
    for (int j = 0; j < 32; ++j) {
        int i = base + j * 256 + t;
        if (i < ETOT) {
            int d = (i < EE) ? ei[EE + i] : (i - EE);
            atomicAdd(&h[d >> 9], 1);
        }
    }
    __syncthreads();
    int orig = h[t];
    lscan[t] = orig;
    __syncthreads();
    for (int off = 1; off < 256; off <<= 1) {
        int add = (t >= off) ? lscan[t - off] : 0;
        __syncthreads();
        lscan[t] += add;
        __syncthreads();
    }
    int excl = lscan[t] - orig;
    __syncthreads();
    lscan[t] = excl;        // exclusive scan (local start of bucket)
    h[t] = excl;            // cursor
    __syncthreads();
    // pass B: place edges into sorted LDS position
    #pragma unroll 4
    for (int j = 0; j < 32; ++j) {
        int i = base + j * 256 + t;
        if (i < ETOT) {
            int sv, dv;
            if (i < EE) { sv = ei[i]; dv = ei[EE + i]; }
            else        { sv = i - EE; dv = sv; }
            int bk = dv >> 9;
            int lp = atomicAdd(&h[bk], 1);
            spair[lp] = ((uint_t)sv << 9) | (uint_t)(dv & 511);
            sbk[lp] = (unsigned char)bk;
        }
    }
    __syncthreads();
    // pass C: linear write — consecutive threads hit consecutive global addrs
    #pragma unroll 4
    for (int j = 0; j < 32; ++j) {
        int i = j * 256 + t;
        if (i < nloc) {
            int bk = sbk[i];
            pairs[sbase[bk] + (i - lscan[bk])] = spair[i];
        }
    }
}

__global__ __launch_bounds__(256) void bucket_build(const uint_t* __restrict__ pairs,
                                                    const int* __restrict__ bbase,
                                                    int* __restrict__ rowptr,
                                                    int* __restrict__ csrc) {
    __shared__ int cnt[512];
    __shared__ int cur[512];
    int b = blockIdx.x;
    int t = threadIdx.x;
    int lo = b << 9;
    int nn = NN - lo; if (nn > 512) nn = 512;
    int e0 = bbase[b];
    int e1 = bbase[b + 1];
    cnt[t] = 0; cnt[t + 256] = 0;
    __syncthreads();
    for (int i = e0 + t; i < e1; i += 256)
        atomicAdd(&cnt[pairs[i] & 511], 1);
    __syncthreads();
    int oc0 = cnt[t], oc1 = cnt[t + 256];
    for (int off = 1; off < 512; off <<= 1) {
        int i0 = t, i1 = t + 256;
        int a0 = cnt[i0] + ((i0 >= off) ? cnt[i0 - off] : 0);
        int a1 = cnt[i1] + ((i1 >= off) ? cnt[i1 - off] : 0);
        __syncthreads();
        cnt[i0] = a0; cnt[i1] = a1;
        __syncthreads();
    }
    int ex0 = cnt[t] - oc0, ex1 = cnt[t + 256] - oc1;
    __syncthreads();
    cur[t] = e0 + ex0; cur[t + 256] = e0 + ex1;
    if (t < nn)       rowptr[lo + t] = e0 + ex0;
    if (t + 256 < nn) rowptr[lo + 256 + t] = e0 + ex1;
    __syncthreads();
    for (int i = e0 + t; i < e1; i += 256) {
        uint_t p = pairs[i];
        int pos = atomicAdd(&cur[p & 511], 1);
        csrc[pos] = (int)(p >> 9);
    }
}

// ================= weight transpose + cast =================

__global__ void castw(const float* __restrict__ proj_w, const float* __restrict__ W,
                      ushort_t* __restrict__ pwT, ushort_t* __restrict__ WT) {
    int id = blockIdx.x * 256 + threadIdx.x;
    if (id < 32768) {
        int n = id >> 8, k = id & 255;
        pwT[id] = (ushort_t)f2bf(proj_w[k * 128 + n]);     // pwT[n][k], K=256
    } else if (id < 81920) {
        int id2 = id - 32768;
        int l = id2 >> 14, r = id2 & 16383;
        int n = r >> 7, k = r & 127;
        WT[id2] = (ushort_t)f2bf(W[l * 16384 + k * 128 + n]); // WT[l][n][k]
    }
}

// ================= bf16 MFMA GEMM: [M x K] @ [K x 128] =================
// mode 0: A bf16-packed. mode 1: A fp32. mode 2: A = elu(bn(aggb)) + hbio
//   (fused BN+ELU+residual staging; hbio updated in-place — race-free since
//    each (row,channel) is read+written by exactly one thread).
// Out: packed-bf16 Cb [M][128] (+bias+elu if bias), optional al logits.

__global__ __launch_bounds__(256) void gemm_mfma(
    const void* __restrict__ Aptr, int mode,
    const ushort_t* __restrict__ Bt, int K,
    const float* __restrict__ bias, ushort_t* __restrict__ Cb,
    const float* __restrict__ a_src, const float* __restrict__ a_dst,
    float* __restrict__ al_s, float* __restrict__ al_d, int M,
    uint_t* __restrict__ hbio, const float* __restrict__ stats,
    const float* __restrict__ bn_gl, const float* __restrict__ bn_bl)
{
    __shared__ uint4 smem[2304];                 // 36864 B
    __shared__ float2 scsh[128];
    ushort_t* As = (ushort_t*)smem;              // [128][72] bf16 (pad 8)
    ushort_t* Bs = As + 128 * 72;                // [128][72]

    int t = threadIdx.x;
    int row0 = blockIdx.x * 128;
    int lane = t & 63, wv = t >> 6;
    int wm = wv >> 1, wn = wv & 1;
    int lr = lane & 15, quad = lane >> 4;

    if (mode == 2 && t < 128) {
        float mu = stats[t] * (1.0f / NN);
        float var = stats[128 + t] * (1.0f / NN) - mu * mu;
        float s = bn_gl[t] * rsqrtf(var + EPS_BN);
        scsh[t] = make_float2(s, bn_bl[t] - mu * s);
    }
    __syncthreads();

    float4v acc[4][4] = {};

    for (int k0 = 0; k0 < K; k0 += 64) {
        if (mode == 1) {
            const float* A = (const float*)Aptr;
            #pragma unroll
            for (int j = 0; j < 8; ++j) {
                int idx = j * 256 + t;
                int row = idx >> 4;
                int c4 = (idx & 15) * 4;
                int gr = row0 + row;
                float4 v = make_float4(0.f, 0.f, 0.f, 0.f);
                if (gr < M) v = *(const float4*)(A + (size_t)gr * K + k0 + c4);
                uint2 u; u.x = pack2(v.x, v.y); u.y = pack2(v.z, v.w);
                *(uint2*)&As[row * 72 + c4] = u;
            }
        } else if (mode == 0) {
            const ushort_t* A = (const ushort_t*)Aptr;
            #pragma unroll
            for (int j = 0; j < 4; ++j) {
                int idx = j * 256 + t;
                int row = idx >> 3;
                int c8 = (idx & 7) * 8;
                int gr = row0 + row;
                uint4 v = make_uint4(0, 0, 0, 0);
                if (gr < M) v = *(const uint4*)(A + (size_t)gr * K + k0 + c8);
                *(uint4*)&As[row * 72 + c8] = v;
            }
        } else {  // mode 2: fused bn+elu+residual
            const uint_t* agg = (const uint_t*)Aptr;
            #pragma unroll
            for (int j = 0; j < 4; ++j) {
                int idx = j * 256 + t;              // 1024 uint4-tasks / k0
                int row = idx >> 3;
                int u4 = idx & 7;
                int gr = row0 + row;
                uint4 o = make_uint4(0, 0, 0, 0);
                if (gr < M) {
                    size_t gi = (size_t)gr * 64 + (k0 >> 1) + u4 * 4;
                    uint4 av = *(const uint4*)(agg + gi);
                    uint4 rv = *(const uint4*)(hbio + gi);
                    int cb = k0 + u4 * 8;
                    uint_t aa[4] = {av.x, av.y, av.z, av.w};
                    uint_t rr[4] = {rv.x, rv.y, rv.z, rv.w};
                    float ov[8];
                    #pragma unroll
                    for (int q = 0; q < 4; ++q) {
                        float2 s0 = scsh[cb + 2 * q];
                        float2 s1 = scsh[cb + 2 * q + 1];
                        float x0 = s0.x * bf_lo(aa[q]) + s0.y;
                        x0 = x0 > 0.f ? x0 : __expf(x0) - 1.f;
                        x0 += bf_lo(rr[q]);
                        float x1 = s1.x * bf_hi(aa[q]) + s1.y;
                        x1 = x1 > 0.f ? x1 : __expf(x1) - 1.f;
                        x1 += bf_hi(rr[q]);
                        ov[2 * q] = x0; ov[2 * q + 1] = x1;
                    }
                    o.x = pack2(ov[0], ov[1]); o.y = pack2(ov[2], ov[3]);
                    o.z = pack2(ov[4], ov[5]); o.w = pack2(ov[6], ov[7]);
                    *(uint4*)(hbio + gi) = o;
                }
                *(uint4*)&As[row * 72 + u4 * 8] = o;
            }
        }
        #pragma unroll
        for (int j = 0; j < 4; ++j) {
            int idx = j * 256 + t;
            int row = idx >> 3;
            int c8 = (idx & 7) * 8;
            uint4 v = *(const uint4*)(Bt + (size_t)row * K + k0 + c8);
            *(uint4*)&Bs[row * 72 + c8] = v;
        }
        __syncthreads();

        const ushort_t* Ab = As + (wm * 64 + lr) * 72 + quad * 8;
        const ushort_t* Bb = Bs + (wn * 64 + lr) * 72 + quad * 8;
        #pragma unroll
        for (int ks = 0; ks < 64; ks += 32) {
            short8 a[4], b[4];
            #pragma unroll
            for (int ti = 0; ti < 4; ++ti) a[ti] = *(const short8*)(Ab + ti * 16 * 72 + ks);
            #pragma unroll
            for (int tj = 0; tj < 4; ++tj) b[tj] = *(const short8*)(Bb + tj * 16 * 72 + ks);
            #pragma unroll
            for (int ti = 0; ti < 4; ++ti)
                #pragma unroll
                for (int tj = 0; tj < 4; ++tj)
                    acc[ti][tj] = __builtin_amdgcn_mfma_f32_16x16x32_bf16(
                        a[ti], b[tj], acc[ti][tj], 0, 0, 0);
        }
        __syncthreads();
    }

    // epilogue: LDS bounce [32][132] fp32; coalesced bf16 stores; fused al logits
    float* sc = (float*)smem;
    for (int ti = 0; ti < 4; ++ti) {
        #pragma unroll
        for (int tj = 0; tj < 4; ++tj) {
            #pragma unroll
            for (int r = 0; r < 4; ++r) {
                int rloc = wm * 16 + quad * 4 + r;
                int col = wn * 64 + tj * 16 + lr;
                sc[rloc * 132 + col] = acc[ti][tj][r];
            }
        }
        __syncthreads();
        #pragma unroll
        for (int j = 0; j < 4; ++j) {
            int idx = j * 256 + t;
            int row = idx >> 5;
            int c4 = (idx & 31) * 4;
            float4 v = *(const float4*)&sc[row * 132 + c4];
            int gr = row0 + (row >> 4) * 64 + ti * 16 + (row & 15);
            if (gr < M) {
                if (bias) {
                    float4 bv = *(const float4*)(bias + c4);
                    v.x += bv.x; v.y += bv.y; v.z += bv.z; v.w += bv.w;
                    v.x = v.x > 0.f ? v.x : __expf(v.x) - 1.f;
                    v.y = v.y > 0.f ? v.y : __expf(v.y) - 1.f;
                    v.z = v.z > 0.f ? v.z : __expf(v.z) - 1.f;
                    v.w = v.w > 0.f ? v.w : __expf(v.w) - 1.f;
                }
                uint2 u; u.x = pack2(v.x, v.y); u.y = pack2(v.z, v.w);
                *(uint2*)(Cb + (size_t)gr * 128 + c4) = u;
            }
        }
        if (al_s) {
            int row = t & 31, head = t >> 5;
            int gr = row0 + (row >> 4) * 64 + ti * 16 + (row & 15);
            if (gr < M) {
                const float* rp = &sc[row * 132 + head * 16];
                const float* spv = a_src + head * 16;
                const float* dpv = a_dst + head * 16;
                float s1 = 0.f, s2 = 0.f;
                #pragma unroll
                for (int c = 0; c < 16; ++c) {
                    float hv = rp[c];
                    s1 += hv * spv[c];
                    s2 += hv * dpv[c];
                }
                al_s[gr * 8 + head] = s1;
                al_d[gr * 8 + head] = s2;
            }
        }
        __syncthreads();
    }
}

// ================= GAT aggregation: wave per dst, bf16 gather, 8x unroll =====

__global__ __launch_bounds__(256) void gat_agg(
    const int* __restrict__ rowptr, const int* __restrict__ csrc,
    const uint_t* __restrict__ h2b, const float* __restrict__ al_s,
    const float* __restrict__ al_d, const float* __restrict__ bias,
    uint_t* __restrict__ outb)
{
    int wv = (blockIdx.x * blockDim.x + threadIdx.x) >> 6;
    int lane = threadIdx.x & 63;
    if (wv >= NN) return;
    int e0 = rowptr[wv], e1 = rowptr[wv + 1];
    int head = lane >> 3;
    int ch = lane * 2;
    float ald = al_d[wv * HEADS + head];
    float acc0 = 0.f, acc1 = 0.f, denom = 0.f;

    int e = e0;
    for (; e + 8 <= e1; e += 8) {
        int ss[8]; float aa[8]; uint_t pp[8];
        #pragma unroll
        for (int k = 0; k < 8; ++k) ss[k] = csrc[e + k];
        #pragma unroll
        for (int k = 0; k < 8; ++k) aa[k] = al_s[ss[k] * HEADS + head];
        #pragma unroll
        for (int k = 0; k < 8; ++k) pp[k] = h2b[(size_t)ss[k] * 64 + lane];
        #pragma unroll
        for (int k = 0; k < 8; ++k) {
            float x = aa[k] + ald;
            x = fmaxf(x, NEG_SLOPE * x);
            float w = __expf(x);
            acc0 += w * bf_lo(pp[k]);
            acc1 += w * bf_hi(pp[k]);
            denom += w;
        }
    }
    for (; e < e1; ++e) {
        int s = csrc[e];
        float a = al_s[s * HEADS + head];
        uint_t p = h2b[(size_t)s * 64 + lane];
        float x = a + ald;
        x = fmaxf(x, NEG_SLOPE * x);
        float w = __expf(x);
        acc0 += w * bf_lo(p);
        acc1 += w * bf_hi(p);
        denom += w;
    }
    float inv = 1.0f / (denom + 1e-16f);
    outb[(size_t)wv * 64 + lane] = pack2(acc0 * inv + bias[ch], acc1 * inv + bias[ch + 1]);
}

// ================= batchnorm stats =================

__global__ void bn_stats(const uint_t* __restrict__ ab, float* stats) {
    int t = threadIdx.x;  // 128: channel t
    int u_idx = t >> 1, hi = t & 1;
    float s = 0.f, q = 0.f;
    for (int r = blockIdx.x; r < NN; r += gridDim.x) {
        uint_t u = ab[(size_t)r * 64 + u_idx];
        float v = hi ? bf_hi(u) : bf_lo(u);
        s += v;
        q += v * v;
    }
    atomicAdd(&stats[t], s);
    atomicAdd(&stats[HID + t], q);
}

// ================= final FC (fused last BN+ELU+residual) =================

__global__ __launch_bounds__(256) void fc_fused(
    const uint_t* __restrict__ aggb, const uint_t* __restrict__ hb,
    const float* __restrict__ stats, const float* __restrict__ g,
    const float* __restrict__ be, const float* __restrict__ w,
    const float* __restrict__ fb, float* __restrict__ out)
{
    __shared__ float2 scsh[128];
    int t = threadIdx.x;
    if (t < 128) {
        float mu = stats[t] * (1.0f / NN);
        float var = stats[128 + t] * (1.0f / NN) - mu * mu;
        float s = g[t] * rsqrtf(var + EPS_BN);
        scsh[t] = make_float2(s, be[t] - mu * s);
    }
    __syncthreads();
    int wv = (blockIdx.x * 256 + t) >> 6;
    int lane = t & 63;
    if (wv >= NN) return;
    uint_t av = aggb[(size_t)wv * 64 + lane];
    uint_t rv = hb[(size_t)wv * 64 + lane];
    int c = lane * 2;
    float2 s0 = scsh[c], s1 = scsh[c + 1];
    float x0 = s0.x * bf_lo(av) + s0.y;
    x0 = x0 > 0.f ? x0 : __expf(x0) - 1.f;
    x0 += bf_lo(rv);
    float x1 = s1.x * bf_hi(av) + s1.y;
    x1 = x1 > 0.f ? x1 : __expf(x1) - 1.f;
    x1 += bf_hi(rv);
    float2 wl = *(const float2*)(w + c);
    float acc = x0 * wl.x + x1 * wl.y;
    #pragma unroll
    for (int off = 32; off > 0; off >>= 1)
        acc += __shfl_down(acc, off, 64);
    if (lane == 0) out[wv] = acc + fb[0];
}

// ================= launch =================

extern "C" void kernel_launch(void* const* d_in, const int* in_sizes, int n_in,
                              void* d_out, int out_size, void* d_ws, size_t ws_size,
                              hipStream_t stream) {
    const float* x       = (const float*)d_in[0];
    const int*   ei      = (const int*)  d_in[1];
    const float* proj_w  = (const float*)d_in[2];
    const float* proj_b  = (const float*)d_in[3];
    const float* W       = (const float*)d_in[4];
    const float* att_src = (const float*)d_in[5];
    const float* att_dst = (const float*)d_in[6];
    const float* conv_b  = (const float*)d_in[7];
    const float* bn_g    = (const float*)d_in[8];
    const float* bn_b    = (const float*)d_in[9];
    const float* fc_w    = (const float*)d_in[10];
    const float* fc_b    = (const float*)d_in[11];
    float* out = (float*)d_out;

    char* p = (char*)d_ws;
    uint_t*   hb   = (uint_t*)p;   p += (size_t)NN * 64 * 4;         // 25.6 MB (bf16x2)
    uint_t*   h2b  = (uint_t*)p;   p += (size_t)NN * 64 * 4;         // 25.6 MB
    uint_t*   aggb = (uint_t*)p;   p += (size_t)NN * 64 * 4;         // 25.6 MB
    uint_t*   pairs = (uint_t*)aggb;                                  // alias (dead early)
    float*    al_s = (float*)p;    p += (size_t)NN * HEADS * 4;
    float*    al_d = (float*)p;    p += (size_t)NN * HEADS * 4;
    int* rowptr    = (int*)p;      p += ((size_t)(NN + 1) * 4 + 255) & ~255ull;
    int* csrc      = (int*)p;      p += (size_t)ETOT * 4;
    int* bcnt      = (int*)p;      p += 1024;                        // memset with stats
    float* stats3  = (float*)p;    p += 3 * 1024;                    // 3 layers x 256 fp32
    int* bbase     = (int*)p;      p += 1024;
    int* lbase     = (int*)p;      p += (size_t)NBLK_A * NB * 4 + 256;
    ushort_t* pwT  = (ushort_t*)p; p += 128 * 256 * 2;
    ushort_t* WT   = (ushort_t*)p; p += 3 * 128 * 128 * 2;
    (void)ws_size; (void)n_in; (void)in_sizes; (void)out_size;

    // zero bcnt + stats3 (adjacent) in one memset
    hipMemsetAsync(bcnt, 0, 4096, stream);

    // --- weights cast/transpose ---
    castw<<<320, 256, 0, stream>>>(proj_w, W, pwT, WT);

    // --- initial projection: hb = bf16(elu(x @ proj_w + b)) ---
    gemm_mfma<<<(NN + 127) / 128, 256, 0, stream>>>(
        x, 1, pwT, 256, proj_b, (ushort_t*)hb, nullptr, nullptr, nullptr, nullptr, NN,
        nullptr, nullptr, nullptr, nullptr);

    // --- CSR build (bucketed counting sort); pairs alias aggb ---
    bucket_hist<<<NBLK_A, 256, 0, stream>>>(ei, bcnt, (int*)lbase);
    bucket_scan<<<1, 256, 0, stream>>>(bcnt, bbase, rowptr);
    bucket_scatter<<<NBLK_A, 256, 0, stream>>>(ei, bbase, (const int*)lbase, pairs);
    bucket_build<<<NB, 256, 0, stream>>>(pairs, bbase, rowptr, csrc);

    for (int l = 0; l < 3; ++l) {
        const ushort_t* WTl = WT + (size_t)l * 128 * 128;
        const float* asl = att_src + (size_t)l * HEADS * CH;
        const float* adl = att_dst + (size_t)l * HEADS * CH;
        const float* cbl = conv_b + (size_t)l * HID;
        float* stl = stats3 + l * 256;

        if (l == 0) {
            gemm_mfma<<<(NN + 127) / 128, 256, 0, stream>>>(
                hb, 0, WTl, 128, nullptr, (ushort_t*)h2b, asl, adl, al_s, al_d, NN,
                nullptr, nullptr, nullptr, nullptr);
        } else {
            // fused: A = elu(bn_{l-1}(aggb)) + hb; hb updated in place
            gemm_mfma<<<(NN + 127) / 128, 256, 0, stream>>>(
                aggb, 2, WTl, 128, nullptr, (ushort_t*)h2b, asl, adl, al_s, al_d, NN,
                hb, stats3 + (l - 1) * 256, bn_g + (size_t)(l - 1) * HID,
                bn_b + (size_t)(l - 1) * HID);
        }
        gat_agg<<<(NN + 3) / 4, 256, 0, stream>>>(rowptr, csrc, h2b, al_s, al_d, cbl, aggb);
        bn_stats<<<512, 128, 0, stream>>>(aggb, stl);
    }

    // fc with fused layer-3 BN+ELU+residual
    fc_fused<<<(NN + 3) / 4, 256, 0, stream>>>(
        aggb, hb, stats3 + 2 * 256, bn_g + 2 * HID, bn_b + 2 * HID, fc_w, fc_b, out);
}

// Round 7
// 819.017 us; speedup vs baseline: 1.7956x; 1.0216x over previous
//
#include <hip/hip_runtime.h>
#include <hip/hip_bf16.h>

#define NN 100000
#define EE 1600000
#define ETOT (NN + EE)
#define HID 128
#define HEADS 8
#define CH 16
#define EPS_BN 1e-5f
#define NEG_SLOPE 0.2f
#define LOG2E 1.4426950408889634f
#define NB 196            // buckets of 512 dst nodes
#define NBLK_A 208        // ceil(ETOT / 8192)

typedef unsigned short ushort_t;
typedef unsigned int uint_t;
typedef __attribute__((ext_vector_type(8))) short short8;
typedef __attribute__((ext_vector_type(4))) float float4v;

__device__ inline uint_t f2bf(float x) {
    __hip_bfloat16 b = __float2bfloat16(x);
    return (uint_t)*reinterpret_cast<unsigned short*>(&b);
}
__device__ inline uint_t pack2(float lo, float hi) {
    return f2bf(lo) | (f2bf(hi) << 16);
}
__device__ inline float bf_lo(uint_t u) { return __uint_as_float(u << 16); }
__device__ inline float bf_hi(uint_t u) { return __uint_as_float(u & 0xffff0000u); }

// ================= CSR build: bucketed counting sort =================

__global__ __launch_bounds__(256) void bucket_hist(const int* __restrict__ ei,
                                                   int* bcnt, int* lbase) {
    __shared__ int h[256];
    int t = threadIdx.x;
    h[t] = 0;
    __syncthreads();
    int base = blockIdx.x * 8192;
    #pragma unroll 4
    for (int j = 0; j < 32; ++j) {
        int i = base + j * 256 + t;
        if (i < ETOT) {
            int d = (i < EE) ? ei[EE + i] : (i - EE);
            atomicAdd(&h[d >> 9], 1);
        }
    }
    __syncthreads();
    // guard t < NB: lbase stride is NB (round-4 crash root cause)
    if (t < NB) {
        int v = h[t];
        lbase[blockIdx.x * NB + t] = v ? atomicAdd(&bcnt[t], v) : 0;
    }
}

__global__ void bucket_scan(const int* __restrict__ bcnt, int* bbase, int* rowptr) {
    __shared__ int s[256];
    int t = threadIdx.x;
    int orig = (t < NB) ? bcnt[t] : 0;
    s[t] = orig;
    __syncthreads();
    for (int off = 1; off < 256; off <<= 1) {
        int add = (t >= off) ? s[t - off] : 0;
        __syncthreads();
        s[t] += add;
        __syncthreads();
    }
    if (t < NB) bbase[t] = s[t] - orig;
    if (t == 0) { bbase[NB] = ETOT; rowptr[NN] = ETOT; }
}

// LDS-staged counting sort per block; linear coalesced write.
__global__ __launch_bounds__(256) void bucket_scatter(const int* __restrict__ ei,
                                                      const int* __restrict__ bbase,
                                                      const int* __restrict__ lbase,
                                                      uint_t* __restrict__ pairs) {
    __shared__ uint_t spair[8192];
    __shared__ unsigned char sbk[8192];
    __shared__ int h[256];
    __shared__ int lscan[256];
    __shared__ int sbase[256];
    int t = threadIdx.x;
    int base = blockIdx.x * 8192;
    int nloc = ETOT - base; if (nloc > 8192) nloc = 8192;
    sbase[t] = (t < NB) ? (bbase[t] + lbase[blockIdx.x * NB + t]) : 0;
    h[t] = 0;
    __syncthreads();
    #pragma unroll 4
    for (int j = 0; j < 32; ++j) {
        int i = base + j * 256 + t;
        if (i < ETOT) {
            int d = (i < EE) ? ei[EE + i] : (i - EE);
            atomicAdd(&h[d >> 9], 1);
        }
    }
    __syncthreads();
    int orig = h[t];
    lscan[t] = orig;
    __syncthreads();
    for (int off = 1; off < 256; off <<= 1) {
        int add = (t >= off) ? lscan[t - off] : 0;
        __syncthreads();
        lscan[t] += add;
        __syncthreads();
    }
    int excl = lscan[t] - orig;
    __syncthreads();
    lscan[t] = excl;
    h[t] = excl;
    __syncthreads();
    #pragma unroll 4
    for (int j = 0; j < 32; ++j) {
        int i = base + j * 256 + t;
        if (i < ETOT) {
            int sv, dv;
            if (i < EE) { sv = ei[i]; dv = ei[EE + i]; }
            else        { sv = i - EE; dv = sv; }
            int bk = dv >> 9;
            int lp = atomicAdd(&h[bk], 1);
            spair[lp] = ((uint_t)sv << 9) | (uint_t)(dv & 511);
            sbk[lp] = (unsigned char)bk;
        }
    }
    __syncthreads();
    #pragma unroll 4
    for (int j = 0; j < 32; ++j) {
        int i = j * 256 + t;
        if (i < nloc) {
            int bk = sbk[i];
            pairs[sbase[bk] + (i - lscan[bk])] = spair[i];
        }
    }
}

__global__ __launch_bounds__(256) void bucket_build(const uint_t* __restrict__ pairs,
                                                    const int* __restrict__ bbase,
                                                    int* __restrict__ rowptr,
                                                    int* __restrict__ csrc) {
    __shared__ int cnt[512];
    __shared__ int cur[512];
    int b = blockIdx.x;
    int t = threadIdx.x;
    int lo = b << 9;
    int nn = NN - lo; if (nn > 512) nn = 512;
    int e0 = bbase[b];
    int e1 = bbase[b + 1];
    cnt[t] = 0; cnt[t + 256] = 0;
    __syncthreads();
    for (int i = e0 + t; i < e1; i += 256)
        atomicAdd(&cnt[pairs[i] & 511], 1);
    __syncthreads();
    int oc0 = cnt[t], oc1 = cnt[t + 256];
    for (int off = 1; off < 512; off <<= 1) {
        int i0 = t, i1 = t + 256;
        int a0 = cnt[i0] + ((i0 >= off) ? cnt[i0 - off] : 0);
        int a1 = cnt[i1] + ((i1 >= off) ? cnt[i1 - off] : 0);
        __syncthreads();
        cnt[i0] = a0; cnt[i1] = a1;
        __syncthreads();
    }
    int ex0 = cnt[t] - oc0, ex1 = cnt[t + 256] - oc1;
    __syncthreads();
    cur[t] = e0 + ex0; cur[t + 256] = e0 + ex1;
    if (t < nn)       rowptr[lo + t] = e0 + ex0;
    if (t + 256 < nn) rowptr[lo + 256 + t] = e0 + ex1;
    __syncthreads();
    for (int i = e0 + t; i < e1; i += 256) {
        uint_t p = pairs[i];
        int pos = atomicAdd(&cur[p & 511], 1);
        csrc[pos] = (int)(p >> 9);
    }
}

// ================= weight transpose + cast (+ zero bcnt/stats) =================

__global__ void castw(const float* __restrict__ proj_w, const float* __restrict__ W,
                      ushort_t* __restrict__ pwT, ushort_t* __restrict__ WT,
                      int* __restrict__ zbuf) {
    int id = blockIdx.x * 256 + threadIdx.x;
    if (id < 1024) zbuf[id] = 0;                           // bcnt + stats3 (4096 B)
    if (id < 32768) {
        int n = id >> 8, k = id & 255;
        pwT[id] = (ushort_t)f2bf(proj_w[k * 128 + n]);     // pwT[n][k], K=256
    } else if (id < 81920) {
        int id2 = id - 32768;
        int l = id2 >> 14, r = id2 & 16383;
        int n = r >> 7, k = r & 127;
        WT[id2] = (ushort_t)f2bf(W[l * 16384 + k * 128 + n]); // WT[l][n][k]
    }
}

// ================= bf16 MFMA GEMM: [M x K] @ [K x 128] =================
// mode 0: A bf16-packed. mode 1: A fp32. mode 2: A = elu(bn(aggb)) + hbio
//   (fused BN+ELU+residual staging; hbio updated in place, race-free).
// al_s/al_d are written PRE-SCALED by log2(e) (consumed by exp2 in gat_agg).

__global__ __launch_bounds__(256) void gemm_mfma(
    const void* __restrict__ Aptr, int mode,
    const ushort_t* __restrict__ Bt, int K,
    const float* __restrict__ bias, ushort_t* __restrict__ Cb,
    const float* __restrict__ a_src, const float* __restrict__ a_dst,
    float* __restrict__ al_s, float* __restrict__ al_d, int M,
    uint_t* __restrict__ hbio, const float* __restrict__ stats,
    const float* __restrict__ bn_gl, const float* __restrict__ bn_bl)
{
    __shared__ uint4 smem[2304];                 // 36864 B
    __shared__ float2 scsh[128];
    ushort_t* As = (ushort_t*)smem;              // [128][72] bf16 (pad 8)
    ushort_t* Bs = As + 128 * 72;                // [128][72]

    int t = threadIdx.x;
    int row0 = blockIdx.x * 128;
    int lane = t & 63, wv = t >> 6;
    int wm = wv >> 1, wn = wv & 1;
    int lr = lane & 15, quad = lane >> 4;

    if (mode == 2 && t < 128) {
        float mu = stats[t] * (1.0f / NN);
        float var = stats[128 + t] * (1.0f / NN) - mu * mu;
        float s = bn_gl[t] * rsqrtf(var + EPS_BN);
        scsh[t] = make_float2(s, bn_bl[t] - mu * s);
    }
    __syncthreads();

    float4v acc[4][4] = {};

    for (int k0 = 0; k0 < K; k0 += 64) {
        if (mode == 1) {
            const float* A = (const float*)Aptr;
            #pragma unroll
            for (int j = 0; j < 8; ++j) {
                int idx = j * 256 + t;
                int row = idx >> 4;
                int c4 = (idx & 15) * 4;
                int gr = row0 + row;
                float4 v = make_float4(0.f, 0.f, 0.f, 0.f);
                if (gr < M) v = *(const float4*)(A + (size_t)gr * K + k0 + c4);
                uint2 u; u.x = pack2(v.x, v.y); u.y = pack2(v.z, v.w);
                *(uint2*)&As[row * 72 + c4] = u;
            }
        } else if (mode == 0) {
            const ushort_t* A = (const ushort_t*)Aptr;
            #pragma unroll
            for (int j = 0; j < 4; ++j) {
                int idx = j * 256 + t;
                int row = idx >> 3;
                int c8 = (idx & 7) * 8;
                int gr = row0 + row;
                uint4 v = make_uint4(0, 0, 0, 0);
                if (gr < M) v = *(const uint4*)(A + (size_t)gr * K + k0 + c8);
                *(uint4*)&As[row * 72 + c8] = v;
            }
        } else {  // mode 2: fused bn+elu+residual
            const uint_t* agg = (const uint_t*)Aptr;
            #pragma unroll
            for (int j = 0; j < 4; ++j) {
                int idx = j * 256 + t;
                int row = idx >> 3;
                int u4 = idx & 7;
                int gr = row0 + row;
                uint4 o = make_uint4(0, 0, 0, 0);
                if (gr < M) {
                    size_t gi = (size_t)gr * 64 + (k0 >> 1) + u4 * 4;
                    uint4 av = *(const uint4*)(agg + gi);
                    uint4 rv = *(const uint4*)(hbio + gi);
                    int cb = k0 + u4 * 8;
                    uint_t aa[4] = {av.x, av.y, av.z, av.w};
                    uint_t rr[4] = {rv.x, rv.y, rv.z, rv.w};
                    float ov[8];
                    #pragma unroll
                    for (int q = 0; q < 4; ++q) {
                        float2 s0 = scsh[cb + 2 * q];
                        float2 s1 = scsh[cb + 2 * q + 1];
                        float x0 = s0.x * bf_lo(aa[q]) + s0.y;
                        x0 = x0 > 0.f ? x0 : __expf(x0) - 1.f;
                        x0 += bf_lo(rr[q]);
                        float x1 = s1.x * bf_hi(aa[q]) + s1.y;
                        x1 = x1 > 0.f ? x1 : __expf(x1) - 1.f;
                        x1 += bf_hi(rr[q]);
                        ov[2 * q] = x0; ov[2 * q + 1] = x1;
                    }
                    o.x = pack2(ov[0], ov[1]); o.y = pack2(ov[2], ov[3]);
                    o.z = pack2(ov[4], ov[5]); o.w = pack2(ov[6], ov[7]);
                    *(uint4*)(hbio + gi) = o;
                }
                *(uint4*)&As[row * 72 + u4 * 8] = o;
            }
        }
        #pragma unroll
        for (int j = 0; j < 4; ++j) {
            int idx = j * 256 + t;
            int row = idx >> 3;
            int c8 = (idx & 7) * 8;
            uint4 v = *(const uint4*)(Bt + (size_t)row * K + k0 + c8);
            *(uint4*)&Bs[row * 72 + c8] = v;
        }
        __syncthreads();

        const ushort_t* Ab = As + (wm * 64 + lr) * 72 + quad * 8;
        const ushort_t* Bb = Bs + (wn * 64 + lr) * 72 + quad * 8;
        #pragma unroll
        for (int ks = 0; ks < 64; ks += 32) {
            short8 a[4], b[4];
            #pragma unroll
            for (int ti = 0; ti < 4; ++ti) a[ti] = *(const short8*)(Ab + ti * 16 * 72 + ks);
            #pragma unroll
            for (int tj = 0; tj < 4; ++tj) b[tj] = *(const short8*)(Bb + tj * 16 * 72 + ks);
            #pragma unroll
            for (int ti = 0; ti < 4; ++ti)
                #pragma unroll
                for (int tj = 0; tj < 4; ++tj)
                    acc[ti][tj] = __builtin_amdgcn_mfma_f32_16x16x32_bf16(
                        a[ti], b[tj], acc[ti][tj], 0, 0, 0);
        }
        __syncthreads();
    }

    // epilogue: 2 rounds of [64][132] fp32 LDS bounce; bf16 stores; al logits
    float* sc = (float*)smem;
    for (int tp = 0; tp < 2; ++tp) {
        #pragma unroll
        for (int th = 0; th < 2; ++th) {
            int ti = tp * 2 + th;
            #pragma unroll
            for (int tj = 0; tj < 4; ++tj) {
                #pragma unroll
                for (int r = 0; r < 4; ++r) {
                    int rloc = wm * 32 + th * 16 + quad * 4 + r;
                    int col = wn * 64 + tj * 16 + lr;
                    sc[rloc * 132 + col] = acc[ti][tj][r];
                }
            }
        }
        __syncthreads();
        #pragma unroll
        for (int j = 0; j < 8; ++j) {
            int idx = j * 256 + t;
            int row = idx >> 5;                 // [0,64)
            int c4 = (idx & 31) * 4;
            float4 v = *(const float4*)&sc[row * 132 + c4];
            int gr = row0 + (row >> 5) * 64 + tp * 32 + (row & 31);
            if (gr < M) {
                if (bias) {
                    float4 bv = *(const float4*)(bias + c4);
                    v.x += bv.x; v.y += bv.y; v.z += bv.z; v.w += bv.w;
                    v.x = v.x > 0.f ? v.x : __expf(v.x) - 1.f;
                    v.y = v.y > 0.f ? v.y : __expf(v.y) - 1.f;
                    v.z = v.z > 0.f ? v.z : __expf(v.z) - 1.f;
                    v.w = v.w > 0.f ? v.w : __expf(v.w) - 1.f;
                }
                uint2 u; u.x = pack2(v.x, v.y); u.y = pack2(v.z, v.w);
                *(uint2*)(Cb + (size_t)gr * 128 + c4) = u;
            }
        }
        if (al_s) {
            #pragma unroll
            for (int jj = 0; jj < 2; ++jj) {
                int task = jj * 256 + t;        // 512 tasks: 64 rows x 8 heads
                int row = task & 63, head = task >> 6;
                int gr = row0 + (row >> 5) * 64 + tp * 32 + (row & 31);
                if (gr < M) {
                    const float* rp = &sc[row * 132 + head * 16];
                    const float* spv = a_src + head * 16;
                    const float* dpv = a_dst + head * 16;
                    float s1 = 0.f, s2 = 0.f;
                    #pragma unroll
                    for (int c = 0; c < 16; ++c) {
                        float hv = rp[c];
                        s1 += hv * spv[c];
                        s2 += hv * dpv[c];
                    }
                    al_s[gr * 8 + head] = s1 * LOG2E;
                    al_d[gr * 8 + head] = s2 * LOG2E;
                }
            }
        }
        __syncthreads();
    }
}

// ================= GAT aggregation: 32 lanes/edge, 4 ch/lane, 2 edge slots ====

__global__ __launch_bounds__(256) void gat_agg(
    const int* __restrict__ rowptr, const int* __restrict__ csrc,
    const uint2* __restrict__ h2b2, const float* __restrict__ al_s,
    const float* __restrict__ al_d, const float* __restrict__ bias,
    uint2* __restrict__ outb2)
{
    int wv = (blockIdx.x * blockDim.x + threadIdx.x) >> 6;
    int lane = threadIdx.x & 63;
    if (wv >= NN) return;
    int eh = lane >> 5;          // edge slot 0/1
    int ln = lane & 31;          // channels 4*ln .. 4*ln+3
    int head = ln >> 2;
    int e0 = rowptr[wv], e1 = rowptr[wv + 1];
    float ald = al_d[wv * 8 + head];            // pre-scaled by log2e
    float a0 = 0.f, a1 = 0.f, a2 = 0.f, a3 = 0.f, denom = 0.f;

    int e = e0;
    for (; e + 8 <= e1; e += 8) {
        int ss[4]; float aa[4]; uint2 pp[4];
        #pragma unroll
        for (int k = 0; k < 4; ++k) ss[k] = csrc[e + 2 * k + eh];
        #pragma unroll
        for (int k = 0; k < 4; ++k) aa[k] = al_s[ss[k] * 8 + head];
        #pragma unroll
        for (int k = 0; k < 4; ++k) pp[k] = h2b2[(size_t)ss[k] * 32 + ln];
        #pragma unroll
        for (int k = 0; k < 4; ++k) {
            float x = aa[k] + ald;
            x = fmaxf(x, NEG_SLOPE * x);
            float w = exp2f(x);
            a0 += w * bf_lo(pp[k].x);
            a1 += w * bf_hi(pp[k].x);
            a2 += w * bf_lo(pp[k].y);
            a3 += w * bf_hi(pp[k].y);
            denom += w;
        }
    }
    for (; e < e1; e += 2) {
        bool valid = (e + eh) < e1;
        int s = csrc[valid ? e + eh : e];
        float a = al_s[s * 8 + head];
        uint2 p = h2b2[(size_t)s * 32 + ln];
        float x = a + ald;
        x = fmaxf(x, NEG_SLOPE * x);
        float w = valid ? exp2f(x) : 0.f;
        a0 += w * bf_lo(p.x);
        a1 += w * bf_hi(p.x);
        a2 += w * bf_lo(p.y);
        a3 += w * bf_hi(p.y);
        denom += w;
    }
    // combine the two edge slots
    a0 += __shfl_xor(a0, 32, 64);
    a1 += __shfl_xor(a1, 32, 64);
    a2 += __shfl_xor(a2, 32, 64);
    a3 += __shfl_xor(a3, 32, 64);
    denom += __shfl_xor(denom, 32, 64);
    if (eh == 0) {
        float inv = 1.0f / (denom + 1e-16f);
        int c = ln * 4;
        uint2 o;
        o.x = pack2(a0 * inv + bias[c],     a1 * inv + bias[c + 1]);
        o.y = pack2(a2 * inv + bias[c + 2], a3 * inv + bias[c + 3]);
        outb2[(size_t)wv * 32 + ln] = o;
    }
}

// ================= batchnorm stats =================

__global__ void bn_stats(const uint_t* __restrict__ ab, float* stats) {
    int t = threadIdx.x;  // 128: channel t
    int u_idx = t >> 1, hi = t & 1;
    float s = 0.f, q = 0.f;
    for (int r0 = blockIdx.x * 4; r0 < NN; r0 += gridDim.x * 4) {
        #pragma unroll
        for (int j = 0; j < 4; ++j) {
            int r = r0 + j;
            if (r < NN) {
                uint_t u = ab[(size_t)r * 64 + u_idx];
                float v = hi ? bf_hi(u) : bf_lo(u);
                s += v;
                q += v * v;
            }
        }
    }
    atomicAdd(&stats[t], s);
    atomicAdd(&stats[HID + t], q);
}

// ================= final FC (fused last BN+ELU+residual) =================

__global__ __launch_bounds__(256) void fc_fused(
    const uint_t* __restrict__ aggb, const uint_t* __restrict__ hb,
    const float* __restrict__ stats, const float* __restrict__ g,
    const float* __restrict__ be, const float* __restrict__ w,
    const float* __restrict__ fb, float* __restrict__ out)
{
    __shared__ float2 scsh[128];
    int t = threadIdx.x;
    if (t < 128) {
        float mu = stats[t] * (1.0f / NN);
        float var = stats[128 + t] * (1.0f / NN) - mu * mu;
        float s = g[t] * rsqrtf(var + EPS_BN);
        scsh[t] = make_float2(s, be[t] - mu * s);
    }
    __syncthreads();
    int wv = (blockIdx.x * 256 + t) >> 6;
    int lane = t & 63;
    if (wv >= NN) return;
    uint_t av = aggb[(size_t)wv * 64 + lane];
    uint_t rv = hb[(size_t)wv * 64 + lane];
    int c = lane * 2;
    float2 s0 = scsh[c], s1 = scsh[c + 1];
    float x0 = s0.x * bf_lo(av) + s0.y;
    x0 = x0 > 0.f ? x0 : __expf(x0) - 1.f;
    x0 += bf_lo(rv);
    float x1 = s1.x * bf_hi(av) + s1.y;
    x1 = x1 > 0.f ? x1 : __expf(x1) - 1.f;
    x1 += bf_hi(rv);
    float2 wl = *(const float2*)(w + c);
    float acc = x0 * wl.x + x1 * wl.y;
    #pragma unroll
    for (int off = 32; off > 0; off >>= 1)
        acc += __shfl_down(acc, off, 64);
    if (lane == 0) out[wv] = acc + fb[0];
}

// ================= launch =================

extern "C" void kernel_launch(void* const* d_in, const int* in_sizes, int n_in,
                              void* d_out, int out_size, void* d_ws, size_t ws_size,
                              hipStream_t stream) {
    const float* x       = (const float*)d_in[0];
    const int*   ei      = (const int*)  d_in[1];
    const float* proj_w  = (const float*)d_in[2];
    const float* proj_b  = (const float*)d_in[3];
    const float* W       = (const float*)d_in[4];
    const float* att_src = (const float*)d_in[5];
    const float* att_dst = (const float*)d_in[6];
    const float* conv_b  = (const float*)d_in[7];
    const float* bn_g    = (const float*)d_in[8];
    const float* bn_b    = (const float*)d_in[9];
    const float* fc_w    = (const float*)d_in[10];
    const float* fc_b    = (const float*)d_in[11];
    float* out = (float*)d_out;

    char* p = (char*)d_ws;
    uint_t*   hb   = (uint_t*)p;   p += (size_t)NN * 64 * 4;         // 25.6 MB (bf16x2)
    uint_t*   h2b  = (uint_t*)p;   p += (size_t)NN * 64 * 4;         // 25.6 MB
    uint_t*   aggb = (uint_t*)p;   p += (size_t)NN * 64 * 4;         // 25.6 MB
    uint_t*   pairs = (uint_t*)aggb;                                  // alias (dead early)
    float*    al_s = (float*)p;    p += (size_t)NN * HEADS * 4;
    float*    al_d = (float*)p;    p += (size_t)NN * HEADS * 4;
    int* rowptr    = (int*)p;      p += ((size_t)(NN + 1) * 4 + 255) & ~255ull;
    int* csrc      = (int*)p;      p += (size_t)ETOT * 4;
    int* bcnt      = (int*)p;      p += 1024;                        // zeroed in castw
    float* stats3  = (float*)p;    p += 3 * 1024;                    // zeroed in castw
    int* bbase     = (int*)p;      p += 1024;
    int* lbase     = (int*)p;      p += (size_t)NBLK_A * NB * 4 + 256;
    ushort_t* pwT  = (ushort_t*)p; p += 128 * 256 * 2;
    ushort_t* WT   = (ushort_t*)p; p += 3 * 128 * 128 * 2;
    (void)ws_size; (void)n_in; (void)in_sizes; (void)out_size;

    // --- weights cast/transpose + zero bcnt/stats3 ---
    castw<<<320, 256, 0, stream>>>(proj_w, W, pwT, WT, bcnt);

    // --- initial projection: hb = bf16(elu(x @ proj_w + b)) ---
    gemm_mfma<<<(NN + 127) / 128, 256, 0, stream>>>(
        x, 1, pwT, 256, proj_b, (ushort_t*)hb, nullptr, nullptr, nullptr, nullptr, NN,
        nullptr, nullptr, nullptr, nullptr);

    // --- CSR build (bucketed counting sort); pairs alias aggb ---
    bucket_hist<<<NBLK_A, 256, 0, stream>>>(ei, bcnt, (int*)lbase);
    bucket_scan<<<1, 256, 0, stream>>>(bcnt, bbase, rowptr);
    bucket_scatter<<<NBLK_A, 256, 0, stream>>>(ei, bbase, (const int*)lbase, pairs);
    bucket_build<<<NB, 256, 0, stream>>>(pairs, bbase, rowptr, csrc);

    for (int l = 0; l < 3; ++l) {
        const ushort_t* WTl = WT + (size_t)l * 128 * 128;
        const float* asl = att_src + (size_t)l * HEADS * CH;
        const float* adl = att_dst + (size_t)l * HEADS * CH;
        const float* cbl = conv_b + (size_t)l * HID;
        float* stl = stats3 + l * 256;

        if (l == 0) {
            gemm_mfma<<<(NN + 127) / 128, 256, 0, stream>>>(
                hb, 0, WTl, 128, nullptr, (ushort_t*)h2b, asl, adl, al_s, al_d, NN,
                nullptr, nullptr, nullptr, nullptr);
        } else {
            gemm_mfma<<<(NN + 127) / 128, 256, 0, stream>>>(
                aggb, 2, WTl, 128, nullptr, (ushort_t*)h2b, asl, adl, al_s, al_d, NN,
                hb, stats3 + (l - 1) * 256, bn_g + (size_t)(l - 1) * HID,
                bn_b + (size_t)(l - 1) * HID);
        }
        gat_agg<<<(NN + 3) / 4, 256, 0, stream>>>(
            rowptr, csrc, (const uint2*)h2b, al_s, al_d, cbl, (uint2*)aggb);
        bn_stats<<<512, 128, 0, stream>>>(aggb, stl);
    }

    // fc with fused layer-3 BN+ELU+residual
    fc_fused<<<(NN + 3) / 4, 256, 0, stream>>>(
        aggb, hb, stats3 + 2 * 256, bn_g + 2 * HID, bn_b + 2 * HID, fc_w, fc_b, out);
}

// Round 8
// 808.552 us; speedup vs baseline: 1.8188x; 1.0129x over previous
//
#include <hip/hip_runtime.h>
#include <hip/hip_bf16.h>

#define NN 100000
#define EE 1600000
#define ETOT (NN + EE)
#define HID 128
#define HEADS 8
#define CH 16
#define EPS_BN 1e-5f
#define NEG_SLOPE 0.2f
#define LOG2E 1.4426950408889634f
#define NB 196            // buckets of 512 dst nodes
#define NBLK_A 208        // ceil(ETOT / 8192)

typedef unsigned short ushort_t;
typedef unsigned int uint_t;
typedef __attribute__((ext_vector_type(8))) short short8;
typedef __attribute__((ext_vector_type(4))) float float4v;

__device__ inline uint_t f2bf(float x) {
    __hip_bfloat16 b = __float2bfloat16(x);
    return (uint_t)*reinterpret_cast<unsigned short*>(&b);
}
__device__ inline uint_t pack2(float lo, float hi) {
    return f2bf(lo) | (f2bf(hi) << 16);
}
__device__ inline float bf_lo(uint_t u) { return __uint_as_float(u << 16); }
__device__ inline float bf_hi(uint_t u) { return __uint_as_float(u & 0xffff0000u); }

// ================= CSR build: bucketed counting sort =================

__global__ __launch_bounds__(256) void bucket_hist(const int* __restrict__ ei,
                                                   int* bcnt, int* lbase) {
    __shared__ int h[256];
    int t = threadIdx.x;
    h[t] = 0;
    __syncthreads();
    int base = blockIdx.x * 8192;
    #pragma unroll 4
    for (int j = 0; j < 32; ++j) {
        int i = base + j * 256 + t;
        if (i < ETOT) {
            int d = (i < EE) ? ei[EE + i] : (i - EE);
            atomicAdd(&h[d >> 9], 1);
        }
    }
    __syncthreads();
    // guard t < NB: lbase stride is NB (round-4 crash root cause)
    if (t < NB) {
        int v = h[t];
        lbase[blockIdx.x * NB + t] = v ? atomicAdd(&bcnt[t], v) : 0;
    }
}

__global__ void bucket_scan(const int* __restrict__ bcnt, int* bbase, int* rowptr) {
    __shared__ int s[256];
    int t = threadIdx.x;
    int orig = (t < NB) ? bcnt[t] : 0;
    s[t] = orig;
    __syncthreads();
    for (int off = 1; off < 256; off <<= 1) {
        int add = (t >= off) ? s[t - off] : 0;
        __syncthreads();
        s[t] += add;
        __syncthreads();
    }
    if (t < NB) bbase[t] = s[t] - orig;
    if (t == 0) { bbase[NB] = ETOT; rowptr[NN] = ETOT; }
}

// LDS-staged counting sort per block; linear coalesced write.
__global__ __launch_bounds__(256) void bucket_scatter(const int* __restrict__ ei,
                                                      const int* __restrict__ bbase,
                                                      const int* __restrict__ lbase,
                                                      uint_t* __restrict__ pairs) {
    __shared__ uint_t spair[8192];
    __shared__ unsigned char sbk[8192];
    __shared__ int h[256];
    __shared__ int lscan[256];
    __shared__ int sbase[256];
    int t = threadIdx.x;
    int base = blockIdx.x * 8192;
    int nloc = ETOT - base; if (nloc > 8192) nloc = 8192;
    sbase[t] = (t < NB) ? (bbase[t] + lbase[blockIdx.x * NB + t]) : 0;
    h[t] = 0;
    __syncthreads();
    #pragma unroll 4
    for (int j = 0; j < 32; ++j) {
        int i = base + j * 256 + t;
        if (i < ETOT) {
            int d = (i < EE) ? ei[EE + i] : (i - EE);
            atomicAdd(&h[d >> 9], 1);
        }
    }
    __syncthreads();
    int orig = h[t];
    lscan[t] = orig;
    __syncthreads();
    for (int off = 1; off < 256; off <<= 1) {
        int add = (t >= off) ? lscan[t - off] : 0;
        __syncthreads();
        lscan[t] += add;
        __syncthreads();
    }
    int excl = lscan[t] - orig;
    __syncthreads();
    lscan[t] = excl;
    h[t] = excl;
    __syncthreads();
    #pragma unroll 4
    for (int j = 0; j < 32; ++j) {
        int i = base + j * 256 + t;
        if (i < ETOT) {
            int sv, dv;
            if (i < EE) { sv = ei[i]; dv = ei[EE + i]; }
            else        { sv = i - EE; dv = sv; }
            int bk = dv >> 9;
            int lp = atomicAdd(&h[bk], 1);
            spair[lp] = ((uint_t)sv << 9) | (uint_t)(dv & 511);
            sbk[lp] = (unsigned char)bk;
        }
    }
    __syncthreads();
    #pragma unroll 4
    for (int j = 0; j < 32; ++j) {
        int i = j * 256 + t;
        if (i < nloc) {
            int bk = sbk[i];
            pairs[sbase[bk] + (i - lscan[bk])] = spair[i];
        }
    }
}

__global__ __launch_bounds__(256) void bucket_build(const uint_t* __restrict__ pairs,
                                                    const int* __restrict__ bbase,
                                                    int* __restrict__ rowptr,
                                                    int* __restrict__ csrc) {
    __shared__ int cnt[512];
    __shared__ int cur[512];
    int b = blockIdx.x;
    int t = threadIdx.x;
    int lo = b << 9;
    int nn = NN - lo; if (nn > 512) nn = 512;
    int e0 = bbase[b];
    int e1 = bbase[b + 1];
    cnt[t] = 0; cnt[t + 256] = 0;
    __syncthreads();
    for (int i = e0 + t; i < e1; i += 256)
        atomicAdd(&cnt[pairs[i] & 511], 1);
    __syncthreads();
    int oc0 = cnt[t], oc1 = cnt[t + 256];
    for (int off = 1; off < 512; off <<= 1) {
        int i0 = t, i1 = t + 256;
        int a0 = cnt[i0] + ((i0 >= off) ? cnt[i0 - off] : 0);
        int a1 = cnt[i1] + ((i1 >= off) ? cnt[i1 - off] : 0);
        __syncthreads();
        cnt[i0] = a0; cnt[i1] = a1;
        __syncthreads();
    }
    int ex0 = cnt[t] - oc0, ex1 = cnt[t + 256] - oc1;
    __syncthreads();
    cur[t] = e0 + ex0; cur[t + 256] = e0 + ex1;
    if (t < nn)       rowptr[lo + t] = e0 + ex0;
    if (t + 256 < nn) rowptr[lo + 256 + t] = e0 + ex1;
    __syncthreads();
    for (int i = e0 + t; i < e1; i += 256) {
        uint_t p = pairs[i];
        int pos = atomicAdd(&cur[p & 511], 1);
        csrc[pos] = (int)(p >> 9);
    }
}

// ================= weight transpose + cast (+ zero bcnt/stats) =================

__global__ void castw(const float* __restrict__ proj_w, const float* __restrict__ W,
                      ushort_t* __restrict__ pwT, ushort_t* __restrict__ WT,
                      int* __restrict__ zbuf) {
    int id = blockIdx.x * 256 + threadIdx.x;
    if (id < 1024) zbuf[id] = 0;                           // bcnt + stats3 (4096 B)
    if (id < 32768) {
        int n = id >> 8, k = id & 255;
        pwT[id] = (ushort_t)f2bf(proj_w[k * 128 + n]);     // pwT[n][k], K=256
    } else if (id < 81920) {
        int id2 = id - 32768;
        int l = id2 >> 14, r = id2 & 16383;
        int n = r >> 7, k = r & 127;
        WT[id2] = (ushort_t)f2bf(W[l * 16384 + k * 128 + n]); // WT[l][n][k]
    }
}

// ================= bf16 MFMA GEMM: [M x K] @ [K x 128] =================
// mode 0: A bf16-packed. mode 1: A fp32. mode 2: A = elu(bn(aggb)) + hbio
//   (fused BN+ELU+residual staging; hbio updated in place, race-free).
// al_s/al_d are written PRE-SCALED by log2(e) (consumed by exp2 in gat_agg).

__global__ __launch_bounds__(256) void gemm_mfma(
    const void* __restrict__ Aptr, int mode,
    const ushort_t* __restrict__ Bt, int K,
    const float* __restrict__ bias, ushort_t* __restrict__ Cb,
    const float* __restrict__ a_src, const float* __restrict__ a_dst,
    float* __restrict__ al_s, float* __restrict__ al_d, int M,
    uint_t* __restrict__ hbio, const float* __restrict__ stats,
    const float* __restrict__ bn_gl, const float* __restrict__ bn_bl)
{
    __shared__ uint4 smem[2304];                 // 36864 B
    __shared__ float2 scsh[128];
    ushort_t* As = (ushort_t*)smem;              // [128][72] bf16 (pad 8)
    ushort_t* Bs = As + 128 * 72;                // [128][72]

    int t = threadIdx.x;
    int row0 = blockIdx.x * 128;
    int lane = t & 63, wv = t >> 6;
    int wm = wv >> 1, wn = wv & 1;
    int lr = lane & 15, quad = lane >> 4;

    if (mode == 2 && t < 128) {
        float mu = stats[t] * (1.0f / NN);
        float var = stats[128 + t] * (1.0f / NN) - mu * mu;
        float s = bn_gl[t] * rsqrtf(var + EPS_BN);
        scsh[t] = make_float2(s, bn_bl[t] - mu * s);
    }
    __syncthreads();

    float4v acc[4][4] = {};

    for (int k0 = 0; k0 < K; k0 += 64) {
        if (mode == 1) {
            const float* A = (const float*)Aptr;
            #pragma unroll
            for (int j = 0; j < 8; ++j) {
                int idx = j * 256 + t;
                int row = idx >> 4;
                int c4 = (idx & 15) * 4;
                int gr = row0 + row;
                float4 v = make_float4(0.f, 0.f, 0.f, 0.f);
                if (gr < M) v = *(const float4*)(A + (size_t)gr * K + k0 + c4);
                uint2 u; u.x = pack2(v.x, v.y); u.y = pack2(v.z, v.w);
                *(uint2*)&As[row * 72 + c4] = u;
            }
        } else if (mode == 0) {
            const ushort_t* A = (const ushort_t*)Aptr;
            #pragma unroll
            for (int j = 0; j < 4; ++j) {
                int idx = j * 256 + t;
                int row = idx >> 3;
                int c8 = (idx & 7) * 8;
                int gr = row0 + row;
                uint4 v = make_uint4(0, 0, 0, 0);
                if (gr < M) v = *(const uint4*)(A + (size_t)gr * K + k0 + c8);
                *(uint4*)&As[row * 72 + c8] = v;
            }
        } else {  // mode 2: fused bn+elu+residual
            const uint_t* agg = (const uint_t*)Aptr;
            #pragma unroll
            for (int j = 0; j < 4; ++j) {
                int idx = j * 256 + t;
                int row = idx >> 3;
                int u4 = idx & 7;
                int gr = row0 + row;
                uint4 o = make_uint4(0, 0, 0, 0);
                if (gr < M) {
                    size_t gi = (size_t)gr * 64 + (k0 >> 1) + u4 * 4;
                    uint4 av = *(const uint4*)(agg + gi);
                    uint4 rv = *(const uint4*)(hbio + gi);
                    int cb = k0 + u4 * 8;
                    uint_t aa[4] = {av.x, av.y, av.z, av.w};
                    uint_t rr[4] = {rv.x, rv.y, rv.z, rv.w};
                    float ov[8];
                    #pragma unroll
                    for (int q = 0; q < 4; ++q) {
                        float2 s0 = scsh[cb + 2 * q];
                        float2 s1 = scsh[cb + 2 * q + 1];
                        float x0 = s0.x * bf_lo(aa[q]) + s0.y;
                        x0 = x0 > 0.f ? x0 : __expf(x0) - 1.f;
                        x0 += bf_lo(rr[q]);
                        float x1 = s1.x * bf_hi(aa[q]) + s1.y;
                        x1 = x1 > 0.f ? x1 : __expf(x1) - 1.f;
                        x1 += bf_hi(rr[q]);
                        ov[2 * q] = x0; ov[2 * q + 1] = x1;
                    }
                    o.x = pack2(ov[0], ov[1]); o.y = pack2(ov[2], ov[3]);
                    o.z = pack2(ov[4], ov[5]); o.w = pack2(ov[6], ov[7]);
                    *(uint4*)(hbio + gi) = o;
                }
                *(uint4*)&As[row * 72 + u4 * 8] = o;
            }
        }
        #pragma unroll
        for (int j = 0; j < 4; ++j) {
            int idx = j * 256 + t;
            int row = idx >> 3;
            int c8 = (idx & 7) * 8;
            uint4 v = *(const uint4*)(Bt + (size_t)row * K + k0 + c8);
            *(uint4*)&Bs[row * 72 + c8] = v;
        }
        __syncthreads();

        const ushort_t* Ab = As + (wm * 64 + lr) * 72 + quad * 8;
        const ushort_t* Bb = Bs + (wn * 64 + lr) * 72 + quad * 8;
        #pragma unroll
        for (int ks = 0; ks < 64; ks += 32) {
            short8 a[4], b[4];
            #pragma unroll
            for (int ti = 0; ti < 4; ++ti) a[ti] = *(const short8*)(Ab + ti * 16 * 72 + ks);
            #pragma unroll
            for (int tj = 0; tj < 4; ++tj) b[tj] = *(const short8*)(Bb + tj * 16 * 72 + ks);
            #pragma unroll
            for (int ti = 0; ti < 4; ++ti)
                #pragma unroll
                for (int tj = 0; tj < 4; ++tj)
                    acc[ti][tj] = __builtin_amdgcn_mfma_f32_16x16x32_bf16(
                        a[ti], b[tj], acc[ti][tj], 0, 0, 0);
        }
        __syncthreads();
    }

    // epilogue: 2 rounds of [64][132] fp32 LDS bounce; bf16 stores; al logits
    float* sc = (float*)smem;
    for (int tp = 0; tp < 2; ++tp) {
        #pragma unroll
        for (int th = 0; th < 2; ++th) {
            int ti = tp * 2 + th;
            #pragma unroll
            for (int tj = 0; tj < 4; ++tj) {
                #pragma unroll
                for (int r = 0; r < 4; ++r) {
                    int rloc = wm * 32 + th * 16 + quad * 4 + r;
                    int col = wn * 64 + tj * 16 + lr;
                    sc[rloc * 132 + col] = acc[ti][tj][r];
                }
            }
        }
        __syncthreads();
        #pragma unroll
        for (int j = 0; j < 8; ++j) {
            int idx = j * 256 + t;
            int row = idx >> 5;                 // [0,64)
            int c4 = (idx & 31) * 4;
            float4 v = *(const float4*)&sc[row * 132 + c4];
            int gr = row0 + (row >> 5) * 64 + tp * 32 + (row & 31);
            if (gr < M) {
                if (bias) {
                    float4 bv = *(const float4*)(bias + c4);
                    v.x += bv.x; v.y += bv.y; v.z += bv.z; v.w += bv.w;
                    v.x = v.x > 0.f ? v.x : __expf(v.x) - 1.f;
                    v.y = v.y > 0.f ? v.y : __expf(v.y) - 1.f;
                    v.z = v.z > 0.f ? v.z : __expf(v.z) - 1.f;
                    v.w = v.w > 0.f ? v.w : __expf(v.w) - 1.f;
                }
                uint2 u; u.x = pack2(v.x, v.y); u.y = pack2(v.z, v.w);
                *(uint2*)(Cb + (size_t)gr * 128 + c4) = u;
            }
        }
        if (al_s) {
            #pragma unroll
            for (int jj = 0; jj < 2; ++jj) {
                int task = jj * 256 + t;        // 512 tasks: 64 rows x 8 heads
                int row = task & 63, head = task >> 6;
                int gr = row0 + (row >> 5) * 64 + tp * 32 + (row & 31);
                if (gr < M) {
                    const float* rp = &sc[row * 132 + head * 16];
                    const float* spv = a_src + head * 16;
                    const float* dpv = a_dst + head * 16;
                    float s1 = 0.f, s2 = 0.f;
                    #pragma unroll
                    for (int c = 0; c < 16; ++c) {
                        float hv = rp[c];
                        s1 += hv * spv[c];
                        s2 += hv * dpv[c];
                    }
                    al_s[gr * 8 + head] = s1 * LOG2E;
                    al_d[gr * 8 + head] = s2 * LOG2E;
                }
            }
        }
        __syncthreads();
    }
}

// ================= GAT aggregation: 16 lanes/edge, 8 ch/lane (uint4 gather) ====
// 4 edge slots per wave; 2-batch pipeline for memory-level parallelism.

__global__ __launch_bounds__(256) void gat_agg(
    const int* __restrict__ rowptr, const int* __restrict__ csrc,
    const uint4* __restrict__ h2b4, const float* __restrict__ al_s,
    const float* __restrict__ al_d, const float* __restrict__ bias,
    uint4* __restrict__ out4)
{
    int wv = (blockIdx.x * blockDim.x + threadIdx.x) >> 6;
    int lane = threadIdx.x & 63;
    if (wv >= NN) return;
    int slot = lane >> 4;        // edge slot 0..3
    int ln = lane & 15;          // channels 8*ln .. 8*ln+7
    int head = ln >> 1;
    int e0 = rowptr[wv], e1 = rowptr[wv + 1];
    float ald = al_d[wv * 8 + head];            // pre-scaled by log2e
    float ac[8] = {};
    float denom = 0.f;

    int e = e0;
    // 2-batch pipelined main loop: 8 edges per iteration
    for (; e + 8 <= e1; e += 8) {
        int sA = csrc[e + slot];
        int sB = csrc[e + 4 + slot];
        float aA = al_s[sA * 8 + head];
        float aB = al_s[sB * 8 + head];
        uint4 pA = h2b4[(size_t)sA * 16 + ln];
        uint4 pB = h2b4[(size_t)sB * 16 + ln];
        float xA = aA + ald; xA = fmaxf(xA, NEG_SLOPE * xA);
        float wA = exp2f(xA);
        float xB = aB + ald; xB = fmaxf(xB, NEG_SLOPE * xB);
        float wB = exp2f(xB);
        uint_t uA[4] = {pA.x, pA.y, pA.z, pA.w};
        uint_t uB[4] = {pB.x, pB.y, pB.z, pB.w};
        #pragma unroll
        for (int q = 0; q < 4; ++q) {
            ac[2 * q]     += wA * bf_lo(uA[q]) + wB * bf_lo(uB[q]);
            ac[2 * q + 1] += wA * bf_hi(uA[q]) + wB * bf_hi(uB[q]);
        }
        denom += wA + wB;
    }
    for (; e < e1; e += 4) {
        int idx = e + slot;
        bool valid = idx < e1;
        int s = csrc[valid ? idx : e];
        float a = al_s[s * 8 + head];
        uint4 p = h2b4[(size_t)s * 16 + ln];
        float x = a + ald; x = fmaxf(x, NEG_SLOPE * x);
        float w = valid ? exp2f(x) : 0.f;
        uint_t u[4] = {p.x, p.y, p.z, p.w};
        #pragma unroll
        for (int q = 0; q < 4; ++q) {
            ac[2 * q]     += w * bf_lo(u[q]);
            ac[2 * q + 1] += w * bf_hi(u[q]);
        }
        denom += w;
    }
    // combine the 4 edge slots (lanes differing in bits 4-5)
    #pragma unroll
    for (int q = 0; q < 8; ++q) {
        ac[q] += __shfl_xor(ac[q], 16, 64);
        ac[q] += __shfl_xor(ac[q], 32, 64);
    }
    denom += __shfl_xor(denom, 16, 64);
    denom += __shfl_xor(denom, 32, 64);
    if (slot == 0) {
        float inv = 1.0f / (denom + 1e-16f);
        int c = ln * 8;
        float4 b0 = *(const float4*)(bias + c);
        float4 b1 = *(const float4*)(bias + c + 4);
        uint4 o;
        o.x = pack2(ac[0] * inv + b0.x, ac[1] * inv + b0.y);
        o.y = pack2(ac[2] * inv + b0.z, ac[3] * inv + b0.w);
        o.z = pack2(ac[4] * inv + b1.x, ac[5] * inv + b1.y);
        o.w = pack2(ac[6] * inv + b1.z, ac[7] * inv + b1.w);
        out4[(size_t)wv * 16 + ln] = o;
    }
}

// ================= batchnorm stats =================

__global__ void bn_stats(const uint_t* __restrict__ ab, float* stats) {
    int t = threadIdx.x;  // 128: channel t
    int u_idx = t >> 1, hi = t & 1;
    float s = 0.f, q = 0.f;
    for (int r0 = blockIdx.x * 4; r0 < NN; r0 += gridDim.x * 4) {
        #pragma unroll
        for (int j = 0; j < 4; ++j) {
            int r = r0 + j;
            if (r < NN) {
                uint_t u = ab[(size_t)r * 64 + u_idx];
                float v = hi ? bf_hi(u) : bf_lo(u);
                s += v;
                q += v * v;
            }
        }
    }
    atomicAdd(&stats[t], s);
    atomicAdd(&stats[HID + t], q);
}

// ================= final FC (fused last BN+ELU+residual) =================

__global__ __launch_bounds__(256) void fc_fused(
    const uint_t* __restrict__ aggb, const uint_t* __restrict__ hb,
    const float* __restrict__ stats, const float* __restrict__ g,
    const float* __restrict__ be, const float* __restrict__ w,
    const float* __restrict__ fb, float* __restrict__ out)
{
    __shared__ float2 scsh[128];
    int t = threadIdx.x;
    if (t < 128) {
        float mu = stats[t] * (1.0f / NN);
        float var = stats[128 + t] * (1.0f / NN) - mu * mu;
        float s = g[t] * rsqrtf(var + EPS_BN);
        scsh[t] = make_float2(s, be[t] - mu * s);
    }
    __syncthreads();
    int wv = (blockIdx.x * 256 + t) >> 6;
    int lane = t & 63;
    if (wv >= NN) return;
    uint_t av = aggb[(size_t)wv * 64 + lane];
    uint_t rv = hb[(size_t)wv * 64 + lane];
    int c = lane * 2;
    float2 s0 = scsh[c], s1 = scsh[c + 1];
    float x0 = s0.x * bf_lo(av) + s0.y;
    x0 = x0 > 0.f ? x0 : __expf(x0) - 1.f;
    x0 += bf_lo(rv);
    float x1 = s1.x * bf_hi(av) + s1.y;
    x1 = x1 > 0.f ? x1 : __expf(x1) - 1.f;
    x1 += bf_hi(rv);
    float2 wl = *(const float2*)(w + c);
    float acc = x0 * wl.x + x1 * wl.y;
    #pragma unroll
    for (int off = 32; off > 0; off >>= 1)
        acc += __shfl_down(acc, off, 64);
    if (lane == 0) out[wv] = acc + fb[0];
}

// ================= launch =================

extern "C" void kernel_launch(void* const* d_in, const int* in_sizes, int n_in,
                              void* d_out, int out_size, void* d_ws, size_t ws_size,
                              hipStream_t stream) {
    const float* x       = (const float*)d_in[0];
    const int*   ei      = (const int*)  d_in[1];
    const float* proj_w  = (const float*)d_in[2];
    const float* proj_b  = (const float*)d_in[3];
    const float* W       = (const float*)d_in[4];
    const float* att_src = (const float*)d_in[5];
    const float* att_dst = (const float*)d_in[6];
    const float* conv_b  = (const float*)d_in[7];
    const float* bn_g    = (const float*)d_in[8];
    const float* bn_b    = (const float*)d_in[9];
    const float* fc_w    = (const float*)d_in[10];
    const float* fc_b    = (const float*)d_in[11];
    float* out = (float*)d_out;

    char* p = (char*)d_ws;
    uint_t*   hb   = (uint_t*)p;   p += (size_t)NN * 64 * 4;         // 25.6 MB (bf16x2)
    uint_t*   h2b  = (uint_t*)p;   p += (size_t)NN * 64 * 4;         // 25.6 MB
    uint_t*   aggb = (uint_t*)p;   p += (size_t)NN * 64 * 4;         // 25.6 MB
    uint_t*   pairs = (uint_t*)aggb;                                  // alias (dead early)
    float*    al_s = (float*)p;    p += (size_t)NN * HEADS * 4;
    float*    al_d = (float*)p;    p += (size_t)NN * HEADS * 4;
    int* rowptr    = (int*)p;      p += ((size_t)(NN + 1) * 4 + 255) & ~255ull;
    int* csrc      = (int*)p;      p += (size_t)ETOT * 4;
    int* bcnt      = (int*)p;      p += 1024;                        // zeroed in castw
    float* stats3  = (float*)p;    p += 3 * 1024;                    // zeroed in castw
    int* bbase     = (int*)p;      p += 1024;
    int* lbase     = (int*)p;      p += (size_t)NBLK_A * NB * 4 + 256;
    ushort_t* pwT  = (ushort_t*)p; p += 128 * 256 * 2;
    ushort_t* WT   = (ushort_t*)p; p += 3 * 128 * 128 * 2;
    (void)ws_size; (void)n_in; (void)in_sizes; (void)out_size;

    // --- weights cast/transpose + zero bcnt/stats3 ---
    castw<<<320, 256, 0, stream>>>(proj_w, W, pwT, WT, bcnt);

    // --- initial projection: hb = bf16(elu(x @ proj_w + b)) ---
    gemm_mfma<<<(NN + 127) / 128, 256, 0, stream>>>(
        x, 1, pwT, 256, proj_b, (ushort_t*)hb, nullptr, nullptr, nullptr, nullptr, NN,
        nullptr, nullptr, nullptr, nullptr);

    // --- CSR build (bucketed counting sort); pairs alias aggb ---
    bucket_hist<<<NBLK_A, 256, 0, stream>>>(ei, bcnt, (int*)lbase);
    bucket_scan<<<1, 256, 0, stream>>>(bcnt, bbase, rowptr);
    bucket_scatter<<<NBLK_A, 256, 0, stream>>>(ei, bbase, (const int*)lbase, pairs);
    bucket_build<<<NB, 256, 0, stream>>>(pairs, bbase, rowptr, csrc);

    for (int l = 0; l < 3; ++l) {
        const ushort_t* WTl = WT + (size_t)l * 128 * 128;
        const float* asl = att_src + (size_t)l * HEADS * CH;
        const float* adl = att_dst + (size_t)l * HEADS * CH;
        const float* cbl = conv_b + (size_t)l * HID;
        float* stl = stats3 + l * 256;

        if (l == 0) {
            gemm_mfma<<<(NN + 127) / 128, 256, 0, stream>>>(
                hb, 0, WTl, 128, nullptr, (ushort_t*)h2b, asl, adl, al_s, al_d, NN,
                nullptr, nullptr, nullptr, nullptr);
        } else {
            gemm_mfma<<<(NN + 127) / 128, 256, 0, stream>>>(
                aggb, 2, WTl, 128, nullptr, (ushort_t*)h2b, asl, adl, al_s, al_d, NN,
                hb, stats3 + (l - 1) * 256, bn_g + (size_t)(l - 1) * HID,
                bn_b + (size_t)(l - 1) * HID);
        }
        gat_agg<<<(NN + 3) / 4, 256, 0, stream>>>(
            rowptr, csrc, (const uint4*)h2b, al_s, al_d, cbl, (uint4*)aggb);
        bn_stats<<<512, 128, 0, stream>>>(aggb, stl);
    }

    // fc with fused layer-3 BN+ELU+residual
    fc_fused<<<(NN + 3) / 4, 256, 0, stream>>>(
        aggb, hb, stats3 + 2 * 256, bn_g + 2 * HID, bn_b + 2 * HID, fc_w, fc_b, out);
}